// Round 4
// baseline (535.645 us; speedup 1.0000x reference)
//
#include <hip/hip_runtime.h>

#define BLK   256
#define TILE  8192
#define NB    64
#define NF    4096

__device__ __forceinline__ int compute_bid(float px, float py, float pz,
                                           float a0x, float a0y, float a0z,
                                           float vx, float vy, float vz) {
    // idx = floor((p - aabb0) / voxel), clamp to [0,3]; bid = ix*16 + iy*4 + iz
    // NOTE: must stay bit-exact vs reference (determines output ORDER).
    int ix = (int)floorf((px - a0x) / vx);
    int iy = (int)floorf((py - a0y) / vy);
    int iz = (int)floorf((pz - a0z) / vz);
    ix = min(max(ix, 0), 3);
    iy = min(max(iy, 0), 3);
    iz = min(max(iz, 0), 3);
    return ix * 16 + iy * 4 + iz;
}

// fx = 63*(p-dmin)/(dmax-dmin)  (value-level only; trilinear is continuous, so
// rounding differences vs reference are ~ulp). Cell bits are a locality hint;
// gather has a global-load fallback, so no exactness requirement on the cell.
__device__ __forceinline__ int compute_key(float px, float py, float pz,
                                           float a0x, float a0y, float a0z,
                                           float vx, float vy, float vz,
                                           const float* s_dn, const float* s_sc,
                                           int& b, float& fx, float& fy, float& fz) {
    b = compute_bid(px, py, pz, a0x, a0y, a0z, vx, vy, vz);
    fx = (px - s_dn[3 * b])     * s_sc[3 * b];
    fy = (py - s_dn[3 * b + 1]) * s_sc[3 * b + 1];
    fz = (pz - s_dn[3 * b + 2]) * s_sc[3 * b + 2];
    int icx = min(max((int)floorf(fx) >> 4, 0), 3);
    int icy = min(max((int)floorf(fy) >> 4, 0), 3);
    int icz = min(max((int)floorf(fz) >> 4, 0), 3);
    return (b << 6) | (icz << 4) | (icy << 2) | icx;
}

// Pass 1: coarse per-tile hist (bucket-major) + fine key per point.
__global__ void hist_kernel(const float* __restrict__ xyz,
                            const float* __restrict__ aabb,
                            const float* __restrict__ dmin,
                            const float* __restrict__ dmax,
                            int* __restrict__ hist64,
                            unsigned short* __restrict__ keys, int N, int G) {
    __shared__ int   sh[NF];
    __shared__ float s_dn[192], s_sc[192];
    const int tid = threadIdx.x, g = blockIdx.x;
    for (int l = tid; l < NF; l += BLK) sh[l] = 0;
    for (int l = tid; l < 192; l += BLK) {
        s_dn[l] = dmin[l];
        s_sc[l] = 63.0f / (dmax[l] - dmin[l]);
    }
    const float a0x = aabb[0], a0y = aabb[1], a0z = aabb[2];
    const float vx = (aabb[3] - a0x) * 0.25f;
    const float vy = (aabb[4] - a0y) * 0.25f;
    const float vz = (aabb[5] - a0z) * 0.25f;
    __syncthreads();
    for (int c = 0; c < TILE / (BLK * 4); ++c) {
        int p0 = g * TILE + c * (BLK * 4) + tid * 4;
        if (p0 + 3 < N) {
            const float4* v4 = (const float4*)(xyz + (size_t)p0 * 3);
            float4 f0 = v4[0], f1 = v4[1], f2 = v4[2];
            int b; float fx, fy, fz;
            int k0 = compute_key(f0.x, f0.y, f0.z, a0x, a0y, a0z, vx, vy, vz, s_dn, s_sc, b, fx, fy, fz);
            int k1 = compute_key(f0.w, f1.x, f1.y, a0x, a0y, a0z, vx, vy, vz, s_dn, s_sc, b, fx, fy, fz);
            int k2 = compute_key(f1.z, f1.w, f2.x, a0x, a0y, a0z, vx, vy, vz, s_dn, s_sc, b, fx, fy, fz);
            int k3 = compute_key(f2.y, f2.z, f2.w, a0x, a0y, a0z, vx, vy, vz, s_dn, s_sc, b, fx, fy, fz);
            atomicAdd(&sh[k0], 1); atomicAdd(&sh[k1], 1);
            atomicAdd(&sh[k2], 1); atomicAdd(&sh[k3], 1);
            keys[p0]     = (unsigned short)k0;
            keys[p0 + 1] = (unsigned short)k1;
            keys[p0 + 2] = (unsigned short)k2;
            keys[p0 + 3] = (unsigned short)k3;
        } else {
            for (int t = 0; t < 4; ++t) {
                int i = p0 + t;
                if (i < N) {
                    int b; float fx, fy, fz;
                    int k = compute_key(xyz[3 * i], xyz[3 * i + 1], xyz[3 * i + 2],
                                        a0x, a0y, a0z, vx, vy, vz, s_dn, s_sc, b, fx, fy, fz);
                    atomicAdd(&sh[k], 1);
                    keys[i] = (unsigned short)k;
                }
            }
        }
    }
    __syncthreads();
    if (tid < NB) {  // coarse count = sum of this bucket's 64 cells
        int s = 0;
        #pragma unroll
        for (int j = 0; j < 64; ++j) s += sh[tid * 64 + j];
        hist64[tid * G + g] = s;
    }
}

// Pass 2: coarse row scan (in place) + totals; block 0 also zeros tot4096.
__global__ void scan_rows_kernel(int* __restrict__ hist, int* __restrict__ tot,
                                 int* __restrict__ tot4096, int G) {
    __shared__ int sh[BLK];
    const int b = blockIdx.x, t = threadIdx.x;
    if (b == 0) for (int l = t; l < NF; l += BLK) tot4096[l] = 0;
    const int L = (G + BLK - 1) / BLK;
    const int lo = t * L;
    const int n = min(L, max(0, G - lo));
    const int base = b * G + lo;
    int s = 0;
    for (int k = 0; k < n; ++k) s += hist[base + k];
    sh[t] = s;
    __syncthreads();
    for (int off = 1; off < BLK; off <<= 1) {
        int v = (t >= off) ? sh[t - off] : 0;
        __syncthreads();
        sh[t] += v;
        __syncthreads();
    }
    int excl = (t == 0) ? 0 : sh[t - 1];
    for (int k = 0; k < n; ++k) {
        int v = hist[base + k];
        hist[base + k] = excl;
        excl += v;
    }
    if (t == BLK - 1) tot[b] = sh[BLK - 1];
}

// Pass 3: fine-bucket totals from the keys array (block-local LDS hist).
__global__ void fhist_kernel(const unsigned short* __restrict__ keys,
                             int* __restrict__ tot4096, int N) {
    __shared__ int sh[NF];
    const int tid = threadIdx.x;
    for (int l = tid; l < NF; l += BLK) sh[l] = 0;
    __syncthreads();
    const int per = (N + gridDim.x - 1) / gridDim.x;
    const int lo = blockIdx.x * per;
    const int hi = min(lo + per, N);
    for (int i = lo + tid; i < hi; i += BLK) atomicAdd(&sh[keys[i]], 1);
    __syncthreads();
    for (int l = tid; l < NF; l += BLK)
        if (sh[l]) atomicAdd(&tot4096[l], sh[l]);
}

// Pass 4: exclusive scan of coarse bucket totals -> global bucket offsets.
__global__ void scan_buckets_kernel(const int* __restrict__ tot, int* __restrict__ off) {
    __shared__ int sh[NB];
    const int t = threadIdx.x;
    sh[t] = tot[t];
    __syncthreads();
    for (int o = 1; o < NB; o <<= 1) {
        int v = (t >= o) ? sh[t - o] : 0;
        __syncthreads();
        sh[t] += v;
        __syncthreads();
    }
    off[t] = (t == 0) ? 0 : sh[t - 1];
}

// Pass 5: exclusive scan of fine totals -> foff[0..NF] and fcnt init.
__global__ void fscan_kernel(const int* __restrict__ tot4096,
                             int* __restrict__ foff, int* __restrict__ fcnt) {
    __shared__ int sh[BLK];
    const int t = threadIdx.x;
    const int L = NF / BLK;  // 16
    int loc[16];
    int s = 0;
    #pragma unroll
    for (int j = 0; j < L; ++j) { loc[j] = tot4096[t * L + j]; s += loc[j]; }
    sh[t] = s;
    __syncthreads();
    for (int o = 1; o < BLK; o <<= 1) {
        int v = (t >= o) ? sh[t - o] : 0;
        __syncthreads();
        sh[t] += v;
        __syncthreads();
    }
    int run = (t == 0) ? 0 : sh[t - 1];
    #pragma unroll
    for (int j = 0; j < L; ++j) {
        foff[t * L + j] = run;
        fcnt[t * L + j] = run;
        run += loc[j];
    }
    if (t == BLK - 1) foff[NF] = run;  // == N
}

// Pass 6: compute stable output position (coarse machinery) + payload scatter
// to the fine-sorted position via atomic counters.
__global__ void scatter_kernel(const float* __restrict__ xyz,
                               const float* __restrict__ dmin,
                               const float* __restrict__ dmax,
                               const unsigned short* __restrict__ keys,
                               const int* __restrict__ hist64,
                               const int* __restrict__ off64,
                               int* __restrict__ fcnt,
                               float4* __restrict__ payload, int N, int G) {
    __shared__ int   s_cnt[NB];
    __shared__ int   s_whist[4][NB];
    __shared__ float s_dn[192], s_sc[192];
    const int tid = threadIdx.x, g = blockIdx.x;
    if (tid < NB) s_cnt[tid] = hist64[tid * G + g] + off64[tid];
    for (int l = tid; l < 192; l += BLK) {
        s_dn[l] = dmin[l];
        s_sc[l] = 63.0f / (dmax[l] - dmin[l]);
    }
    __syncthreads();

    const int lane = tid & 63;
    const int wv = tid >> 6;
    const unsigned long long lt = (1ull << lane) - 1ull;

    for (int c = 0; c < TILE / BLK; ++c) {
        int i = g * TILE + c * BLK + tid;
        bool valid = (i < N);
        int k = 0, b = 0;
        float fx = 0.0f, fy = 0.0f, fz = 0.0f;
        if (valid) {
            k = keys[i];
            b = k >> 6;
            float px = xyz[3 * i], py = xyz[3 * i + 1], pz = xyz[3 * i + 2];
            fx = (px - s_dn[3 * b])     * s_sc[3 * b];
            fy = (py - s_dn[3 * b + 1]) * s_sc[3 * b + 1];
            fz = (pz - s_dn[3 * b + 2]) * s_sc[3 * b + 2];
        }
        ((int*)s_whist)[tid] = 0;
        __syncthreads();
        // match-any over the 6-bit bucket id within the wave (stable rank)
        unsigned long long m = __ballot(valid);
        #pragma unroll
        for (int q = 0; q < 6; ++q) {
            unsigned long long bal = __ballot((b >> q) & 1);
            m &= ((b >> q) & 1) ? bal : ~bal;
        }
        int rank = __popcll(m & lt);
        if (valid && rank == 0) s_whist[wv][b] = __popcll(m);
        __syncthreads();
        if (valid) {
            int outpos = s_cnt[b] + rank;
            for (int w2 = 0; w2 < wv; ++w2) outpos += s_whist[w2][b];
            int fpos = atomicAdd(&fcnt[k], 1);   // any order within fine bucket
            payload[fpos] = make_float4(fx, fy, fz, __int_as_float(outpos));
        }
        __syncthreads();
        if (tid < NB)
            s_cnt[tid] += s_whist[0][tid] + s_whist[1][tid] +
                          s_whist[2][tid] + s_whist[3][tid];
        __syncthreads();
    }
}

// Pass 7: one block per fine bucket. Stage 17^3 halo region in LDS, then
// trilinear taps from LDS; scattered 4B write to the stable output position.
__global__ void __launch_bounds__(BLK) gather_kernel(
        const float* __restrict__ vol,
        const float4* __restrict__ payload,
        const int* __restrict__ foff,
        float* __restrict__ out) {
    __shared__ float sv[17 * 17 * 17];  // 19652 B -> 8 blocks/CU
    const int tid = threadIdx.x, k = blockIdx.x;
    const int b = k >> 6;
    const int bz = ((k >> 4) & 3) * 16, by = ((k >> 2) & 3) * 16, bx = (k & 3) * 16;
    const float* vb = vol + ((size_t)b << 18);
    for (int l = tid; l < 17 * 17 * 17; l += BLK) {
        int z = l / 289, r = l - z * 289, y = r / 17, x = r - y * 17;
        int gz = bz + z, gy = by + y, gx = bx + x;
        sv[l] = (gz < 64 && gy < 64 && gx < 64)
                    ? vb[(gz << 12) + (gy << 6) + gx] : 0.0f;
    }
    __syncthreads();
    const int lo = foff[k];
    const int n = foff[k + 1] - lo;
    for (int j = tid; j < n; j += BLK) {
        float4 p = payload[lo + j];
        float x0f = floorf(p.x), y0f = floorf(p.y), z0f = floorf(p.z);
        float wx = p.x - x0f, wy = p.y - y0f, wz = p.z - z0f;
        int x0 = (int)x0f, y0 = (int)y0f, z0 = (int)z0f;
        auto F = [&](int gz, int gy, int gx) -> float {
            if ((unsigned)gz >= 64u || (unsigned)gy >= 64u || (unsigned)gx >= 64u)
                return 0.0f;  // grid_sample zeros padding
            int lz = gz - bz, ly = gy - by, lx = gx - bx;
            if ((unsigned)lz <= 16u && (unsigned)ly <= 16u && (unsigned)lx <= 16u)
                return sv[lz * 289 + ly * 17 + lx];
            return vb[(gz << 12) + (gy << 6) + gx];  // out-of-cell fallback (rare)
        };
        float s = 0.0f;
        s += (1.0f - wz) * (1.0f - wy) * (1.0f - wx) * F(z0,     y0,     x0);
        s += (1.0f - wz) * (1.0f - wy) * wx          * F(z0,     y0,     x0 + 1);
        s += (1.0f - wz) * wy          * (1.0f - wx) * F(z0,     y0 + 1, x0);
        s += (1.0f - wz) * wy          * wx          * F(z0,     y0 + 1, x0 + 1);
        s += wz          * (1.0f - wy) * (1.0f - wx) * F(z0 + 1, y0,     x0);
        s += wz          * (1.0f - wy) * wx          * F(z0 + 1, y0,     x0 + 1);
        s += wz          * wy          * (1.0f - wx) * F(z0 + 1, y0 + 1, x0);
        s += wz          * wy          * wx          * F(z0 + 1, y0 + 1, x0 + 1);
        out[__float_as_int(p.w)] = s;
    }
}

extern "C" void kernel_launch(void* const* d_in, const int* in_sizes, int n_in,
                              void* d_out, int out_size, void* d_ws, size_t ws_size,
                              hipStream_t stream) {
    const float* xyz  = (const float*)d_in[0];
    const float* aabb = (const float*)d_in[1];
    const float* vol  = (const float*)d_in[2];
    const float* dmin = (const float*)d_in[3];
    const float* dmax = (const float*)d_in[4];
    float* out = (float*)d_out;
    const int N = in_sizes[0] / 3;
    const int G = (N + TILE - 1) / TILE;

    // ws layout (~76 MB at N=4.19M):
    // payload[N]f4 | keys[N]u16 | hist64[64*G] | tot64 | off64 | tot4096 | foff[NF+1] | fcnt[NF]
    char* ws = (char*)d_ws;
    size_t o = 0;
    float4* payload = (float4*)(ws + o);          o += (size_t)N * 16;
    unsigned short* keys = (unsigned short*)(ws + o); o += ((size_t)N * 2 + 255) & ~255ull;
    int* hist64  = (int*)(ws + o);                o += ((size_t)NB * G * 4 + 255) & ~255ull;
    int* tot64   = (int*)(ws + o);                o += 256;
    int* off64   = (int*)(ws + o);                o += 256;
    int* tot4096 = (int*)(ws + o);                o += (size_t)NF * 4;
    int* foff    = (int*)(ws + o);                o += ((size_t)(NF + 1) * 4 + 255) & ~255ull;
    int* fcnt    = (int*)(ws + o);                o += (size_t)NF * 4;

    hist_kernel<<<G, BLK, 0, stream>>>(xyz, aabb, dmin, dmax, hist64, keys, N, G);
    scan_rows_kernel<<<NB, BLK, 0, stream>>>(hist64, tot64, tot4096, G);
    fhist_kernel<<<128, BLK, 0, stream>>>(keys, tot4096, N);
    scan_buckets_kernel<<<1, NB, 0, stream>>>(tot64, off64);
    fscan_kernel<<<1, BLK, 0, stream>>>(tot4096, foff, fcnt);
    scatter_kernel<<<G, BLK, 0, stream>>>(xyz, dmin, dmax, keys, hist64, off64,
                                          fcnt, payload, N, G);
    gather_kernel<<<NF, BLK, 0, stream>>>(vol, payload, foff, out);
}

// Round 5
// 353.958 us; speedup vs baseline: 1.5133x; 1.5133x over previous
//
#include <hip/hip_runtime.h>

#define BLK    256
#define TILE_C 4096    // coarse scatter tile (round-3 proven)
#define NB     64
#define NF     4096
#define TILE_F 16384   // fine tile2 (contiguous range of coarse-sorted array)
#define FBLK   512

__device__ __forceinline__ int compute_bid(float px, float py, float pz,
                                           float a0x, float a0y, float a0z,
                                           float vx, float vy, float vz) {
    // idx = floor((p - aabb0) / voxel), clamp to [0,3]; bid = ix*16 + iy*4 + iz
    // Must stay bit-exact vs reference (determines output ORDER).
    int ix = (int)floorf((px - a0x) / vx);
    int iy = (int)floorf((py - a0y) / vy);
    int iz = (int)floorf((pz - a0z) / vz);
    ix = min(max(ix, 0), 3);
    iy = min(max(iy, 0), 3);
    iz = min(max(iz, 0), 3);
    return ix * 16 + iy * 4 + iz;
}

// ---------- Pass 1: per-tile coarse 64-bin histograms (bucket-major) ----------
__global__ void hist_kernel(const float* __restrict__ xyz,
                            const float* __restrict__ aabb,
                            int* __restrict__ hist, int N, int G) {
    __shared__ int s_h[NB];
    const int tid = threadIdx.x, g = blockIdx.x;
    if (tid < NB) s_h[tid] = 0;
    __syncthreads();
    const float a0x = aabb[0], a0y = aabb[1], a0z = aabb[2];
    const float vx = (aabb[3] - a0x) * 0.25f;
    const float vy = (aabb[4] - a0y) * 0.25f;
    const float vz = (aabb[5] - a0z) * 0.25f;
    for (int c = 0; c < TILE_C / (BLK * 4); ++c) {
        int p0 = g * TILE_C + c * (BLK * 4) + tid * 4;
        if (p0 + 3 < N) {
            const float4* v4 = (const float4*)(xyz + (size_t)p0 * 3);
            float4 f0 = v4[0], f1 = v4[1], f2 = v4[2];
            atomicAdd(&s_h[compute_bid(f0.x, f0.y, f0.z, a0x, a0y, a0z, vx, vy, vz)], 1);
            atomicAdd(&s_h[compute_bid(f0.w, f1.x, f1.y, a0x, a0y, a0z, vx, vy, vz)], 1);
            atomicAdd(&s_h[compute_bid(f1.z, f1.w, f2.x, a0x, a0y, a0z, vx, vy, vz)], 1);
            atomicAdd(&s_h[compute_bid(f2.y, f2.z, f2.w, a0x, a0y, a0z, vx, vy, vz)], 1);
        } else {
            for (int t = 0; t < 4; ++t) {
                int i = p0 + t;
                if (i < N)
                    atomicAdd(&s_h[compute_bid(xyz[3 * i], xyz[3 * i + 1], xyz[3 * i + 2],
                                               a0x, a0y, a0z, vx, vy, vz)], 1);
            }
        }
    }
    __syncthreads();
    if (tid < NB) hist[tid * G + g] = s_h[tid];
}

// ---------- Pass 2a: per-bucket row scan (in place) + totals ----------
__global__ void scan_rows_kernel(int* __restrict__ hist, int* __restrict__ tot, int G) {
    __shared__ int sh[BLK];
    const int b = blockIdx.x, t = threadIdx.x;
    const int L = (G + BLK - 1) / BLK;
    const int lo = t * L;
    const int n = min(L, max(0, G - lo));
    const int base = b * G + lo;
    int s = 0;
    for (int k = 0; k < n; ++k) s += hist[base + k];
    sh[t] = s;
    __syncthreads();
    for (int off = 1; off < BLK; off <<= 1) {
        int v = (t >= off) ? sh[t - off] : 0;
        __syncthreads();
        sh[t] += v;
        __syncthreads();
    }
    int excl = (t == 0) ? 0 : sh[t - 1];
    for (int k = 0; k < n; ++k) {
        int v = hist[base + k];
        hist[base + k] = excl;
        excl += v;
    }
    if (t == BLK - 1) tot[b] = sh[BLK - 1];
}

// ---------- Pass 2b: scan 64 bucket totals -> global bucket offsets ----------
__global__ void scan_buckets_kernel(const int* __restrict__ tot, int* __restrict__ off) {
    __shared__ int sh[NB];
    const int t = threadIdx.x;
    sh[t] = tot[t];
    __syncthreads();
    for (int o = 1; o < NB; o <<= 1) {
        int v = (t >= o) ? sh[t - o] : 0;
        __syncthreads();
        sh[t] += v;
        __syncthreads();
    }
    off[t] = (t == 0) ? 0 : sh[t - 1];
}

// ---------- Pass 3: COARSE stable scatter: payloadC[outpos]=(fx,fy,fz,key12),
// key16[outpos]=key12.  Runs of ~64 pts/bucket/tile -> write amp ~1. ----------
__global__ void scatterC_kernel(const float* __restrict__ xyz,
                                const float* __restrict__ aabb,
                                const float* __restrict__ dmin,
                                const float* __restrict__ dmax,
                                const int* __restrict__ hist,
                                const int* __restrict__ off,
                                float4* __restrict__ payloadC,
                                unsigned short* __restrict__ key16,
                                int N, int G) {
    __shared__ int   s_cnt[NB];
    __shared__ int   s_whist[4][NB];
    __shared__ float s_dn[192], s_sc[192];
    const int tid = threadIdx.x, g = blockIdx.x;
    if (tid < NB) s_cnt[tid] = hist[tid * G + g] + off[tid];
    for (int l = tid; l < 192; l += BLK) {
        s_dn[l] = dmin[l];
        s_sc[l] = 63.0f / (dmax[l] - dmin[l]);
    }
    const float a0x = aabb[0], a0y = aabb[1], a0z = aabb[2];
    const float vx = (aabb[3] - a0x) * 0.25f;
    const float vy = (aabb[4] - a0y) * 0.25f;
    const float vz = (aabb[5] - a0z) * 0.25f;
    __syncthreads();

    const int lane = tid & 63;
    const int wv = tid >> 6;
    const unsigned long long lt = (1ull << lane) - 1ull;

    for (int c = 0; c < TILE_C / BLK; ++c) {
        int i = g * TILE_C + c * BLK + tid;
        bool valid = (i < N);
        int b = 0, key = 0;
        float fx = 0.0f, fy = 0.0f, fz = 0.0f;
        if (valid) {
            float px = xyz[3 * i], py = xyz[3 * i + 1], pz = xyz[3 * i + 2];
            b = compute_bid(px, py, pz, a0x, a0y, a0z, vx, vy, vz);
            fx = (px - s_dn[3 * b])     * s_sc[3 * b];
            fy = (py - s_dn[3 * b + 1]) * s_sc[3 * b + 1];
            fz = (pz - s_dn[3 * b + 2]) * s_sc[3 * b + 2];
            int icx = min(max((int)floorf(fx) >> 4, 0), 3);
            int icy = min(max((int)floorf(fy) >> 4, 0), 3);
            int icz = min(max((int)floorf(fz) >> 4, 0), 3);
            key = (b << 6) | (icz << 4) | (icy << 2) | icx;
        }
        ((int*)s_whist)[tid] = 0;
        __syncthreads();
        // stable wave rank: match-any over the 6-bit bucket id
        unsigned long long m = __ballot(valid);
        #pragma unroll
        for (int q = 0; q < 6; ++q) {
            unsigned long long bal = __ballot((b >> q) & 1);
            m &= ((b >> q) & 1) ? bal : ~bal;
        }
        int rank = __popcll(m & lt);
        if (valid && rank == 0) s_whist[wv][b] = __popcll(m);
        __syncthreads();
        if (valid) {
            int pos = s_cnt[b] + rank;
            for (int w2 = 0; w2 < wv; ++w2) pos += s_whist[w2][b];
            payloadC[pos] = make_float4(fx, fy, fz, __int_as_float(key));
            key16[pos] = (unsigned short)key;
        }
        __syncthreads();
        if (tid < NB)
            s_cnt[tid] += s_whist[0][tid] + s_whist[1][tid] +
                          s_whist[2][tid] + s_whist[3][tid];
        __syncthreads();
    }
}

// ---------- Pass 4: per-tile2 fine histograms (tile-major hist2[t2][k]) ----------
__global__ void fhist2_kernel(const unsigned short* __restrict__ key16,
                              int* __restrict__ hist2, int N) {
    __shared__ int sh[NF];
    const int tid = threadIdx.x, t2 = blockIdx.x;
    for (int l = tid; l < NF; l += BLK) sh[l] = 0;
    __syncthreads();
    const int lo = t2 * TILE_F;
    const int n = min(TILE_F, N - lo);
    for (int j = tid; j < n; j += BLK) atomicAdd(&sh[key16[lo + j]], 1);
    __syncthreads();
    for (int l = tid; l < NF; l += BLK) hist2[(size_t)t2 * NF + l] = sh[l];
}

// ---------- Pass 5: column running-sum over tile2s (in place) + fine totals ----------
__global__ void colscan2_kernel(int* __restrict__ hist2, int* __restrict__ tot4096, int T2) {
    const int k = blockIdx.x * BLK + threadIdx.x;  // one fine bucket per thread
    int run = 0;
    for (int t2 = 0; t2 < T2; ++t2) {
        int v = hist2[(size_t)t2 * NF + k];
        hist2[(size_t)t2 * NF + k] = run;
        run += v;
    }
    tot4096[k] = run;
}

// ---------- Pass 6: scan fine totals -> foff[0..NF] ----------
__global__ void fscan_kernel(const int* __restrict__ tot4096, int* __restrict__ foff) {
    __shared__ int sh[BLK];
    const int t = threadIdx.x;
    const int L = NF / BLK;  // 16
    int loc[16];
    int s = 0;
    #pragma unroll
    for (int j = 0; j < L; ++j) { loc[j] = tot4096[t * L + j]; s += loc[j]; }
    sh[t] = s;
    __syncthreads();
    for (int o = 1; o < BLK; o <<= 1) {
        int v = (t >= o) ? sh[t - o] : 0;
        __syncthreads();
        sh[t] += v;
        __syncthreads();
    }
    int run = (t == 0) ? 0 : sh[t - 1];
    #pragma unroll
    for (int j = 0; j < L; ++j) {
        foff[t * L + j] = run;
        run += loc[j];
    }
    if (t == BLK - 1) foff[NF] = run;  // == N
}

// ---------- Pass 7: FINE scatter within coarse order. tile2 is contiguous in
// ~1 coarse bucket -> ~256 pts per cell -> 4KB runs -> write amp ~1.
// Fine rank via LDS returning atomics (block-local, fast, no ordering need). ----------
__global__ void __launch_bounds__(FBLK) scatterF_kernel(
        const float4* __restrict__ payloadC,
        const int* __restrict__ hist2,
        const int* __restrict__ foff,
        float4* __restrict__ payloadF, int N) {
    __shared__ int s_fb[NF];  // 16 KB
    const int tid = threadIdx.x, t2 = blockIdx.x;
    for (int l = tid; l < NF; l += FBLK)
        s_fb[l] = foff[l] + hist2[(size_t)t2 * NF + l];
    __syncthreads();
    const int lo = t2 * TILE_F;
    const int n = min(TILE_F, N - lo);
    for (int j = tid; j < n; j += FBLK) {
        float4 p = payloadC[lo + j];
        int key = __float_as_int(p.w);
        int fpos = atomicAdd(&s_fb[key], 1);          // order within cell: free
        payloadF[fpos] = make_float4(p.x, p.y, p.z, __int_as_float(lo + j));  // .w = outpos
    }
}

// ---------- Pass 8: one block per fine bucket; 17^3 halo staged in LDS. ----------
__global__ void __launch_bounds__(BLK) gather_fine_kernel(
        const float* __restrict__ vol,
        const float4* __restrict__ payloadF,
        const int* __restrict__ foff,
        float* __restrict__ out) {
    __shared__ float sv[17 * 17 * 17];  // 19652 B
    const int tid = threadIdx.x;
    // XCD-contiguous swizzle: XCD x owns k in [x*512, (x+1)*512) = 8 coarse
    // buckets -> out-write windows (2 MB) and vol stay in that XCD's L2.
    const int nb = gridDim.x, d = blockIdx.x;
    const int k = (nb % 8 == 0) ? (d % 8) * (nb / 8) + (d / 8) : d;
    const int b = k >> 6;
    const int bz = ((k >> 4) & 3) * 16, by = ((k >> 2) & 3) * 16, bx = (k & 3) * 16;
    const float* vb = vol + ((size_t)b << 18);
    for (int l = tid; l < 17 * 17 * 17; l += BLK) {
        int z = l / 289, r = l - z * 289, y = r / 17, x = r - y * 17;
        int gz = bz + z, gy = by + y, gx = bx + x;
        sv[l] = (gz < 64 && gy < 64 && gx < 64)
                    ? vb[(gz << 12) + (gy << 6) + gx] : 0.0f;
    }
    __syncthreads();
    const int lo = foff[k];
    const int n = foff[k + 1] - lo;
    for (int j = tid; j < n; j += BLK) {
        float4 p = payloadF[lo + j];
        float x0f = floorf(p.x), y0f = floorf(p.y), z0f = floorf(p.z);
        float wx = p.x - x0f, wy = p.y - y0f, wz = p.z - z0f;
        int x0 = (int)x0f, y0 = (int)y0f, z0 = (int)z0f;
        auto F = [&](int gz, int gy, int gx) -> float {
            if ((unsigned)gz >= 64u || (unsigned)gy >= 64u || (unsigned)gx >= 64u)
                return 0.0f;  // grid_sample zeros padding
            int lz = gz - bz, ly = gy - by, lx = gx - bx;
            if ((unsigned)lz <= 16u && (unsigned)ly <= 16u && (unsigned)lx <= 16u)
                return sv[lz * 289 + ly * 17 + lx];
            return vb[(gz << 12) + (gy << 6) + gx];  // rare edge fallback
        };
        float s = 0.0f;
        s += (1.0f - wz) * (1.0f - wy) * (1.0f - wx) * F(z0,     y0,     x0);
        s += (1.0f - wz) * (1.0f - wy) * wx          * F(z0,     y0,     x0 + 1);
        s += (1.0f - wz) * wy          * (1.0f - wx) * F(z0,     y0 + 1, x0);
        s += (1.0f - wz) * wy          * wx          * F(z0,     y0 + 1, x0 + 1);
        s += wz          * (1.0f - wy) * (1.0f - wx) * F(z0 + 1, y0,     x0);
        s += wz          * (1.0f - wy) * wx          * F(z0 + 1, y0,     x0 + 1);
        s += wz          * wy          * (1.0f - wx) * F(z0 + 1, y0 + 1, x0);
        s += wz          * wy          * wx          * F(z0 + 1, y0 + 1, x0 + 1);
        out[__float_as_int(p.w)] = s;
    }
}

// ---------- Fallback gather (round-3, proven): coarse order, global taps ----------
__global__ void gather_fallback_kernel(const float* __restrict__ vol,
                                       const float4* __restrict__ payloadC,
                                       float* __restrict__ out, int N) {
    int nb = gridDim.x, d = blockIdx.x;
    int lb = (nb % 8 == 0) ? (d % 8) * (nb / 8) + (d / 8) : d;
    int j = lb * BLK + threadIdx.x;
    if (j >= N) return;
    float4 p = payloadC[j];
    int b = __float_as_int(p.w) >> 6;
    float x0f = floorf(p.x), y0f = floorf(p.y), z0f = floorf(p.z);
    float wx = p.x - x0f, wy = p.y - y0f, wz = p.z - z0f;
    int x0 = (int)x0f, y0 = (int)y0f, z0 = (int)z0f;
    const float* vb = vol + ((size_t)b << 18);
    auto F = [&](int zi, int yi, int xi) -> float {
        if ((unsigned)zi >= 64u || (unsigned)yi >= 64u || (unsigned)xi >= 64u)
            return 0.0f;
        return vb[(zi << 12) + (yi << 6) + xi];
    };
    float s = 0.0f;
    s += (1.0f - wz) * (1.0f - wy) * (1.0f - wx) * F(z0,     y0,     x0);
    s += (1.0f - wz) * (1.0f - wy) * wx          * F(z0,     y0,     x0 + 1);
    s += (1.0f - wz) * wy          * (1.0f - wx) * F(z0,     y0 + 1, x0);
    s += (1.0f - wz) * wy          * wx          * F(z0,     y0 + 1, x0 + 1);
    s += wz          * (1.0f - wy) * (1.0f - wx) * F(z0 + 1, y0,     x0);
    s += wz          * (1.0f - wy) * wx          * F(z0 + 1, y0,     x0 + 1);
    s += wz          * wy          * (1.0f - wx) * F(z0 + 1, y0 + 1, x0);
    s += wz          * wy          * wx          * F(z0 + 1, y0 + 1, x0 + 1);
    out[j] = s;
}

extern "C" void kernel_launch(void* const* d_in, const int* in_sizes, int n_in,
                              void* d_out, int out_size, void* d_ws, size_t ws_size,
                              hipStream_t stream) {
    const float* xyz  = (const float*)d_in[0];
    const float* aabb = (const float*)d_in[1];
    const float* vol  = (const float*)d_in[2];
    const float* dmin = (const float*)d_in[3];
    const float* dmax = (const float*)d_in[4];
    float* out = (float*)d_out;
    const int N  = in_sizes[0] / 3;
    const int G  = (N + TILE_C - 1) / TILE_C;
    const int T2 = (N + TILE_F - 1) / TILE_F;

    auto align = [](size_t x) { return (x + 255) & ~(size_t)255; };
    char* ws = (char*)d_ws;
    size_t o = 0;
    float4* payloadC = (float4*)(ws + o);            o += align((size_t)N * 16);
    unsigned short* key16 = (unsigned short*)(ws + o); o += align((size_t)N * 2);
    int* hist64 = (int*)(ws + o);                    o += align((size_t)NB * G * 4);
    int* tot64  = (int*)(ws + o);                    o += 256;
    int* off64  = (int*)(ws + o);                    o += 256;
    size_t o_base = o;
    float4* payloadF = (float4*)(ws + o);            o += align((size_t)N * 16);
    int* hist2   = (int*)(ws + o);                   o += align((size_t)T2 * NF * 4);
    int* tot4096 = (int*)(ws + o);                   o += align((size_t)NF * 4);
    int* foff    = (int*)(ws + o);                   o += align((size_t)(NF + 1) * 4);
    const bool fine = (ws_size >= o) && (N >= TILE_F);
    (void)o_base;

    hist_kernel<<<G, BLK, 0, stream>>>(xyz, aabb, hist64, N, G);
    scan_rows_kernel<<<NB, BLK, 0, stream>>>(hist64, tot64, G);
    scan_buckets_kernel<<<1, NB, 0, stream>>>(tot64, off64);
    scatterC_kernel<<<G, BLK, 0, stream>>>(xyz, aabb, dmin, dmax, hist64, off64,
                                           payloadC, key16, N, G);
    if (fine) {
        fhist2_kernel<<<T2, BLK, 0, stream>>>(key16, hist2, N);
        colscan2_kernel<<<NF / BLK, BLK, 0, stream>>>(hist2, tot4096, T2);
        fscan_kernel<<<1, BLK, 0, stream>>>(tot4096, foff);
        scatterF_kernel<<<T2, FBLK, 0, stream>>>(payloadC, hist2, foff, payloadF, N);
        gather_fine_kernel<<<NF, BLK, 0, stream>>>(vol, payloadF, foff, out);
    } else {
        gather_fallback_kernel<<<(N + BLK - 1) / BLK, BLK, 0, stream>>>(
            vol, payloadC, out, N);
    }
}

// Round 6
// 283.072 us; speedup vs baseline: 1.8923x; 1.2504x over previous
//
#include <hip/hip_runtime.h>

#define BLK    256
#define TILE_C 4096    // coarse scatter tile
#define NB     64
#define NF     4096
#define TILE_F 16384   // fine tile2 (contiguous range of coarse-sorted array)
#define FBLK   512

__device__ __forceinline__ int compute_bid(float px, float py, float pz,
                                           float a0x, float a0y, float a0z,
                                           float vx, float vy, float vz) {
    // Must stay bit-exact vs reference (plain divide!) — determines output ORDER.
    int ix = (int)floorf((px - a0x) / vx);
    int iy = (int)floorf((py - a0y) / vy);
    int iz = (int)floorf((pz - a0z) / vz);
    ix = min(max(ix, 0), 3);
    iy = min(max(iy, 0), 3);
    iz = min(max(iz, 0), 3);
    return ix * 16 + iy * 4 + iz;
}

// ---------- Pass 1: per-tile coarse 64-bin histograms (bucket-major) ----------
__global__ void hist_kernel(const float* __restrict__ xyz,
                            const float* __restrict__ aabb,
                            int* __restrict__ hist, int N, int G) {
    __shared__ int s_h[NB];
    const int tid = threadIdx.x, g = blockIdx.x;
    if (tid < NB) s_h[tid] = 0;
    __syncthreads();
    const float a0x = aabb[0], a0y = aabb[1], a0z = aabb[2];
    const float vx = (aabb[3] - a0x) * 0.25f;
    const float vy = (aabb[4] - a0y) * 0.25f;
    const float vz = (aabb[5] - a0z) * 0.25f;
    for (int c = 0; c < TILE_C / (BLK * 4); ++c) {
        int p0 = g * TILE_C + c * (BLK * 4) + tid * 4;
        if (p0 + 3 < N) {
            const float4* v4 = (const float4*)(xyz + (size_t)p0 * 3);
            float4 f0 = v4[0], f1 = v4[1], f2 = v4[2];
            atomicAdd(&s_h[compute_bid(f0.x, f0.y, f0.z, a0x, a0y, a0z, vx, vy, vz)], 1);
            atomicAdd(&s_h[compute_bid(f0.w, f1.x, f1.y, a0x, a0y, a0z, vx, vy, vz)], 1);
            atomicAdd(&s_h[compute_bid(f1.z, f1.w, f2.x, a0x, a0y, a0z, vx, vy, vz)], 1);
            atomicAdd(&s_h[compute_bid(f2.y, f2.z, f2.w, a0x, a0y, a0z, vx, vy, vz)], 1);
        } else {
            for (int t = 0; t < 4; ++t) {
                int i = p0 + t;
                if (i < N)
                    atomicAdd(&s_h[compute_bid(xyz[3 * i], xyz[3 * i + 1], xyz[3 * i + 2],
                                               a0x, a0y, a0z, vx, vy, vz)], 1);
            }
        }
    }
    __syncthreads();
    if (tid < NB) hist[tid * G + g] = s_h[tid];
}

// ---------- Pass 2: per-bucket row scan (in place) + totals; block0 zeros tot4096 ----------
__global__ void scan_rows_kernel(int* __restrict__ hist, int* __restrict__ tot,
                                 int* __restrict__ tot4096, int G) {
    __shared__ int sh[BLK];
    const int b = blockIdx.x, t = threadIdx.x;
    if (b == 0) for (int l = t; l < NF; l += BLK) tot4096[l] = 0;
    const int L = (G + BLK - 1) / BLK;
    const int lo = t * L;
    const int n = min(L, max(0, G - lo));
    const int base = b * G + lo;
    int s = 0;
    for (int k = 0; k < n; ++k) s += hist[base + k];
    sh[t] = s;
    __syncthreads();
    for (int off = 1; off < BLK; off <<= 1) {
        int v = (t >= off) ? sh[t - off] : 0;
        __syncthreads();
        sh[t] += v;
        __syncthreads();
    }
    int excl = (t == 0) ? 0 : sh[t - 1];
    for (int k = 0; k < n; ++k) {
        int v = hist[base + k];
        hist[base + k] = excl;
        excl += v;
    }
    if (t == BLK - 1) tot[b] = sh[BLK - 1];
}

// ---------- Pass 3: COARSE stable scatter (bucket offsets scanned in-block) ----------
__global__ void scatterC_kernel(const float* __restrict__ xyz,
                                const float* __restrict__ aabb,
                                const float* __restrict__ dmin,
                                const float* __restrict__ dmax,
                                const int* __restrict__ hist,
                                const int* __restrict__ tot64,
                                float4* __restrict__ payloadC,
                                unsigned short* __restrict__ key16,
                                int N, int G) {
    __shared__ int   s_cnt[NB];
    __shared__ int   s_off[NB];
    __shared__ int   s_whist[4][NB];
    __shared__ float s_dn[192], s_sc[192];
    const int tid = threadIdx.x, g = blockIdx.x;
    if (tid < NB) s_off[tid] = tot64[tid];
    for (int l = tid; l < 192; l += BLK) {
        s_dn[l] = dmin[l];
        s_sc[l] = 63.0f / (dmax[l] - dmin[l]);
    }
    __syncthreads();
    // in-block inclusive scan of the 64 totals
    for (int o = 1; o < NB; o <<= 1) {
        int v = (tid < NB && tid >= o) ? s_off[tid - o] : 0;
        __syncthreads();
        if (tid < NB) s_off[tid] += v;
        __syncthreads();
    }
    if (tid < NB)
        s_cnt[tid] = hist[tid * G + g] + (tid == 0 ? 0 : s_off[tid - 1]);
    const float a0x = aabb[0], a0y = aabb[1], a0z = aabb[2];
    const float vx = (aabb[3] - a0x) * 0.25f;
    const float vy = (aabb[4] - a0y) * 0.25f;
    const float vz = (aabb[5] - a0z) * 0.25f;
    __syncthreads();

    const int lane = tid & 63;
    const int wv = tid >> 6;
    const unsigned long long lt = (1ull << lane) - 1ull;

    for (int c = 0; c < TILE_C / BLK; ++c) {
        int i = g * TILE_C + c * BLK + tid;
        bool valid = (i < N);
        int b = 0, key = 0;
        float fx = 0.0f, fy = 0.0f, fz = 0.0f;
        if (valid) {
            float px = xyz[3 * i], py = xyz[3 * i + 1], pz = xyz[3 * i + 2];
            b = compute_bid(px, py, pz, a0x, a0y, a0z, vx, vy, vz);
            fx = (px - s_dn[3 * b])     * s_sc[3 * b];
            fy = (py - s_dn[3 * b + 1]) * s_sc[3 * b + 1];
            fz = (pz - s_dn[3 * b + 2]) * s_sc[3 * b + 2];
            int icx = min(max((int)floorf(fx) >> 4, 0), 3);
            int icy = min(max((int)floorf(fy) >> 4, 0), 3);
            int icz = min(max((int)floorf(fz) >> 4, 0), 3);
            key = (b << 6) | (icz << 4) | (icy << 2) | icx;
        }
        ((int*)s_whist)[tid] = 0;
        __syncthreads();
        // stable wave rank: match-any over the 6-bit bucket id
        unsigned long long m = __ballot(valid);
        #pragma unroll
        for (int q = 0; q < 6; ++q) {
            unsigned long long bal = __ballot((b >> q) & 1);
            m &= ((b >> q) & 1) ? bal : ~bal;
        }
        int rank = __popcll(m & lt);
        if (valid && rank == 0) s_whist[wv][b] = __popcll(m);
        __syncthreads();
        if (valid) {
            int pos = s_cnt[b] + rank;
            for (int w2 = 0; w2 < wv; ++w2) pos += s_whist[w2][b];
            payloadC[pos] = make_float4(fx, fy, fz, __int_as_float(key));
            key16[pos] = (unsigned short)key;
        }
        __syncthreads();
        if (tid < NB)
            s_cnt[tid] += s_whist[0][tid] + s_whist[1][tid] +
                          s_whist[2][tid] + s_whist[3][tid];
        __syncthreads();
    }
}

// ---------- Pass 4: per-tile2 fine histograms (row write) + global totals ----------
__global__ void fhist2_kernel(const unsigned short* __restrict__ key16,
                              int* __restrict__ hist2,
                              int* __restrict__ tot4096, int N) {
    __shared__ int sh[NF];
    const int tid = threadIdx.x, t2 = blockIdx.x;
    for (int l = tid; l < NF; l += BLK) sh[l] = 0;
    __syncthreads();
    const int lo = t2 * TILE_F;
    const int n = min(TILE_F, N - lo);
    for (int j = tid; j < n; j += BLK) atomicAdd(&sh[key16[lo + j]], 1);
    __syncthreads();
    for (int l = tid; l < NF; l += BLK) {
        int c = sh[l];
        hist2[(size_t)t2 * NF + l] = c;
        if (c) atomicAdd(&tot4096[l], c);
    }
}

// ---------- Pass 5: scan fine totals -> foff[0..NF]; init fcnt = foff ----------
__global__ void fscan_kernel(const int* __restrict__ tot4096,
                             int* __restrict__ foff, int* __restrict__ fcnt) {
    __shared__ int sh[BLK];
    const int t = threadIdx.x;
    const int L = NF / BLK;  // 16
    int loc[16];
    int s = 0;
    #pragma unroll
    for (int j = 0; j < L; ++j) { loc[j] = tot4096[t * L + j]; s += loc[j]; }
    sh[t] = s;
    __syncthreads();
    for (int o = 1; o < BLK; o <<= 1) {
        int v = (t >= o) ? sh[t - o] : 0;
        __syncthreads();
        sh[t] += v;
        __syncthreads();
    }
    int run = (t == 0) ? 0 : sh[t - 1];
    #pragma unroll
    for (int j = 0; j < L; ++j) {
        foff[t * L + j] = run;
        fcnt[t * L + j] = run;
        run += loc[j];
    }
    if (t == BLK - 1) foff[NF] = run;  // == N
}

// ---------- Pass 6: FINE scatter. Range RESERVATION via one global atomicAdd
// per present cell (order within a fine cell is free — outpos travels with the
// point), then per-point LDS returning atomics for slots. No column scan. ----------
__global__ void __launch_bounds__(FBLK) scatterF_kernel(
        const float4* __restrict__ payloadC,
        const int* __restrict__ hist2,
        int* __restrict__ fcnt,
        float4* __restrict__ payloadF, int N) {
    __shared__ int s_fb[NF];  // 16 KB
    const int tid = threadIdx.x, t2 = blockIdx.x;
    for (int l = tid; l < NF; l += FBLK) {
        int c = hist2[(size_t)t2 * NF + l];
        s_fb[l] = c ? atomicAdd(&fcnt[l], c) : 0;
    }
    __syncthreads();
    const int lo = t2 * TILE_F;
    const int n = min(TILE_F, N - lo);
    for (int j = tid; j < n; j += FBLK) {
        float4 p = payloadC[lo + j];
        int key = __float_as_int(p.w);
        int fpos = atomicAdd(&s_fb[key], 1);
        payloadF[fpos] = make_float4(p.x, p.y, p.z, __int_as_float(lo + j));  // .w = outpos
    }
}

// ---------- Pass 7: one block per fine cell; 17^3 halo in LDS; clamp-safe taps ----------
__global__ void __launch_bounds__(BLK) gather_fine_kernel(
        const float* __restrict__ vol,
        const float4* __restrict__ payloadF,
        const int* __restrict__ foff,
        float* __restrict__ out) {
    __shared__ float sv[17 * 17 * 17];  // 19652 B
    const int tid = threadIdx.x;
    // XCD-contiguous swizzle: XCD x owns a contiguous range of sorted output.
    const int nb = gridDim.x, d = blockIdx.x;
    const int k = (nb % 8 == 0) ? (d % 8) * (nb / 8) + (d / 8) : d;
    const int b = k >> 6;
    const int bz = ((k >> 4) & 3) * 16, by = ((k >> 2) & 3) * 16, bx = (k & 3) * 16;
    const float* vb = vol + ((size_t)b << 18);
    for (int l = tid; l < 17 * 17 * 17; l += BLK) {
        int z = l / 289, r = l - z * 289, y = r / 17, x = r - y * 17;
        int gz = bz + z, gy = by + y, gx = bx + x;
        sv[l] = (gz < 64 && gy < 64 && gx < 64)
                    ? vb[(gz << 12) + (gy << 6) + gx] : 0.0f;
    }
    __syncthreads();
    const int lo = foff[k];
    const int n = foff[k + 1] - lo;
    for (int j = tid; j < n; j += BLK) {
        float4 p = payloadF[lo + j];
        // Clamp to [0,63]: no-op for in-aabb points; keeps indices inside the
        // staged region and consistent with scatterC's cell bits for any input.
        float fx = fminf(fmaxf(p.x, 0.0f), 63.0f);
        float fy = fminf(fmaxf(p.y, 0.0f), 63.0f);
        float fz = fminf(fmaxf(p.z, 0.0f), 63.0f);
        float x0f = floorf(fx), y0f = floorf(fy), z0f = floorf(fz);
        float wx = fx - x0f, wy = fy - y0f, wz = fz - z0f;
        int lx = (int)x0f - bx, ly = (int)y0f - by, lz = (int)z0f - bz;
        int base = lz * 289 + ly * 17 + lx;
        float v000 = sv[base],        v001 = sv[base + 1];
        float v010 = sv[base + 17],   v011 = sv[base + 18];
        float v100 = sv[base + 289],  v101 = sv[base + 290];
        float v110 = sv[base + 306],  v111 = sv[base + 307];
        float c00 = v000 + wx * (v001 - v000);
        float c01 = v010 + wx * (v011 - v010);
        float c10 = v100 + wx * (v101 - v100);
        float c11 = v110 + wx * (v111 - v110);
        float c0 = c00 + wy * (c01 - c00);
        float c1 = c10 + wy * (c11 - c10);
        out[__float_as_int(p.w)] = c0 + wz * (c1 - c0);
    }
}

// ---------- Fallback gather (coarse order, global taps) ----------
__global__ void gather_fallback_kernel(const float* __restrict__ vol,
                                       const float4* __restrict__ payloadC,
                                       float* __restrict__ out, int N) {
    int nb = gridDim.x, d = blockIdx.x;
    int lb = (nb % 8 == 0) ? (d % 8) * (nb / 8) + (d / 8) : d;
    int j = lb * BLK + threadIdx.x;
    if (j >= N) return;
    float4 p = payloadC[j];
    int b = __float_as_int(p.w) >> 6;
    float x0f = floorf(p.x), y0f = floorf(p.y), z0f = floorf(p.z);
    float wx = p.x - x0f, wy = p.y - y0f, wz = p.z - z0f;
    int x0 = (int)x0f, y0 = (int)y0f, z0 = (int)z0f;
    const float* vb = vol + ((size_t)b << 18);
    auto F = [&](int zi, int yi, int xi) -> float {
        if ((unsigned)zi >= 64u || (unsigned)yi >= 64u || (unsigned)xi >= 64u)
            return 0.0f;
        return vb[(zi << 12) + (yi << 6) + xi];
    };
    float s = 0.0f;
    s += (1.0f - wz) * (1.0f - wy) * (1.0f - wx) * F(z0,     y0,     x0);
    s += (1.0f - wz) * (1.0f - wy) * wx          * F(z0,     y0,     x0 + 1);
    s += (1.0f - wz) * wy          * (1.0f - wx) * F(z0,     y0 + 1, x0);
    s += (1.0f - wz) * wy          * wx          * F(z0,     y0 + 1, x0 + 1);
    s += wz          * (1.0f - wy) * (1.0f - wx) * F(z0 + 1, y0,     x0);
    s += wz          * (1.0f - wy) * wx          * F(z0 + 1, y0,     x0 + 1);
    s += wz          * wy          * (1.0f - wx) * F(z0 + 1, y0 + 1, x0);
    s += wz          * wy          * wx          * F(z0 + 1, y0 + 1, x0 + 1);
    out[j] = s;
}

extern "C" void kernel_launch(void* const* d_in, const int* in_sizes, int n_in,
                              void* d_out, int out_size, void* d_ws, size_t ws_size,
                              hipStream_t stream) {
    const float* xyz  = (const float*)d_in[0];
    const float* aabb = (const float*)d_in[1];
    const float* vol  = (const float*)d_in[2];
    const float* dmin = (const float*)d_in[3];
    const float* dmax = (const float*)d_in[4];
    float* out = (float*)d_out;
    const int N  = in_sizes[0] / 3;
    const int G  = (N + TILE_C - 1) / TILE_C;
    const int T2 = (N + TILE_F - 1) / TILE_F;

    auto align = [](size_t x) { return (x + 255) & ~(size_t)255; };
    char* ws = (char*)d_ws;
    size_t o = 0;
    float4* payloadC = (float4*)(ws + o);              o += align((size_t)N * 16);
    unsigned short* key16 = (unsigned short*)(ws + o); o += align((size_t)N * 2);
    int* hist64 = (int*)(ws + o);                      o += align((size_t)NB * G * 4);
    int* tot64  = (int*)(ws + o);                      o += 256;
    float4* payloadF = (float4*)(ws + o);              o += align((size_t)N * 16);
    int* hist2   = (int*)(ws + o);                     o += align((size_t)T2 * NF * 4);
    int* tot4096 = (int*)(ws + o);                     o += align((size_t)NF * 4);
    int* foff    = (int*)(ws + o);                     o += align((size_t)(NF + 1) * 4);
    int* fcnt    = (int*)(ws + o);                     o += align((size_t)NF * 4);
    const bool fine = (ws_size >= o) && (N >= TILE_F);

    hist_kernel<<<G, BLK, 0, stream>>>(xyz, aabb, hist64, N, G);
    scan_rows_kernel<<<NB, BLK, 0, stream>>>(hist64, tot64, tot4096, G);
    scatterC_kernel<<<G, BLK, 0, stream>>>(xyz, aabb, dmin, dmax, hist64, tot64,
                                           payloadC, key16, N, G);
    if (fine) {
        fhist2_kernel<<<T2, BLK, 0, stream>>>(key16, hist2, tot4096, N);
        fscan_kernel<<<1, BLK, 0, stream>>>(tot4096, foff, fcnt);
        scatterF_kernel<<<T2, FBLK, 0, stream>>>(payloadC, hist2, fcnt, payloadF, N);
        gather_fine_kernel<<<NF, BLK, 0, stream>>>(vol, payloadF, foff, out);
    } else {
        gather_fallback_kernel<<<(N + BLK - 1) / BLK, BLK, 0, stream>>>(
            vol, payloadC, out, N);
    }
}

// Round 7
// 280.055 us; speedup vs baseline: 1.9126x; 1.0108x over previous
//
#include <hip/hip_runtime.h>

#define NB     64
#define NF     4096
#define TILE   16384
#define HBLK   1024
#define DBLK   1024   // 16 waves
#define GBLK   256
#define SBLK   256
#define FB_TILE 4096

// bit-exact bid (order-determining — plain divides, matches reference)
__device__ __forceinline__ int compute_bid(float px, float py, float pz,
                                           float a0x, float a0y, float a0z,
                                           float vx, float vy, float vz) {
    int ix = (int)floorf((px - a0x) / vx);
    int iy = (int)floorf((py - a0y) / vy);
    int iz = (int)floorf((pz - a0z) / vz);
    ix = min(max(ix, 0), 3);
    iy = min(max(iy, 0), 3);
    iz = min(max(iz, 0), 3);
    return ix * 16 + iy * 4 + iz;
}

// Quantize: q = round(fx*256) in [0,16128] (14 bits, 8 frac). Must be the
// IDENTICAL expression in hist and scatterD so keys agree.
__device__ __forceinline__ void quant_point(float px, float py, float pz,
        float a0x, float a0y, float a0z, float vx, float vy, float vz,
        const float* s_dn, const float* s_sc,
        int& b, int& qx, int& qy, int& qz, int& key) {
    b = compute_bid(px, py, pz, a0x, a0y, a0z, vx, vy, vz);
    float fx = (px - s_dn[3 * b])     * s_sc[3 * b];
    float fy = (py - s_dn[3 * b + 1]) * s_sc[3 * b + 1];
    float fz = (pz - s_dn[3 * b + 2]) * s_sc[3 * b + 2];
    qx = min(max(__float2int_rn(fx * 256.0f), 0), 16128);
    qy = min(max(__float2int_rn(fy * 256.0f), 0), 16128);
    qz = min(max(__float2int_rn(fz * 256.0f), 0), 16128);
    key = (b << 6) | ((qz >> 12) << 4) | ((qy >> 12) << 2) | (qx >> 12);
}

// ---- Pass 1: per-tile fine hist row + coarse hist row + global fine totals ----
__global__ void __launch_bounds__(HBLK) hist_kernel(
        const float* __restrict__ xyz, const float* __restrict__ aabb,
        const float* __restrict__ dmin, const float* __restrict__ dmax,
        int* __restrict__ hist64, int* __restrict__ hist2,
        int* __restrict__ tot4096, int N, int T) {
    __shared__ int   sh[NF];
    __shared__ float s_dn[192], s_sc[192];
    const int tid = threadIdx.x, g = blockIdx.x;
    for (int l = tid; l < NF; l += HBLK) sh[l] = 0;
    if (tid < 192) { s_dn[tid] = dmin[tid]; s_sc[tid] = 63.0f / (dmax[tid] - dmin[tid]); }
    const float a0x = aabb[0], a0y = aabb[1], a0z = aabb[2];
    const float vx = (aabb[3] - a0x) * 0.25f;
    const float vy = (aabb[4] - a0y) * 0.25f;
    const float vz = (aabb[5] - a0z) * 0.25f;
    __syncthreads();
    for (int c = 0; c < TILE / (HBLK * 4); ++c) {
        int p0 = g * TILE + c * (HBLK * 4) + tid * 4;
        int b, qx, qy, qz, k;
        if (p0 + 3 < N) {
            const float4* v4 = (const float4*)(xyz + (size_t)p0 * 3);
            float4 f0 = v4[0], f1 = v4[1], f2 = v4[2];
            quant_point(f0.x, f0.y, f0.z, a0x, a0y, a0z, vx, vy, vz, s_dn, s_sc, b, qx, qy, qz, k);
            atomicAdd(&sh[k], 1);
            quant_point(f0.w, f1.x, f1.y, a0x, a0y, a0z, vx, vy, vz, s_dn, s_sc, b, qx, qy, qz, k);
            atomicAdd(&sh[k], 1);
            quant_point(f1.z, f1.w, f2.x, a0x, a0y, a0z, vx, vy, vz, s_dn, s_sc, b, qx, qy, qz, k);
            atomicAdd(&sh[k], 1);
            quant_point(f2.y, f2.z, f2.w, a0x, a0y, a0z, vx, vy, vz, s_dn, s_sc, b, qx, qy, qz, k);
            atomicAdd(&sh[k], 1);
        } else {
            for (int t = 0; t < 4; ++t) {
                int i = p0 + t;
                if (i < N) {
                    quant_point(xyz[3 * i], xyz[3 * i + 1], xyz[3 * i + 2],
                                a0x, a0y, a0z, vx, vy, vz, s_dn, s_sc, b, qx, qy, qz, k);
                    atomicAdd(&sh[k], 1);
                }
            }
        }
    }
    __syncthreads();
    for (int l = tid; l < NF; l += HBLK) {
        int c = sh[l];
        hist2[(size_t)g * NF + l] = c;
        if (c) atomicAdd(&tot4096[l], c);
    }
    if (tid < NB) {
        int s = 0;
        #pragma unroll
        for (int j = 0; j < 64; ++j) s += sh[tid * 64 + j];
        hist64[tid * T + g] = s;
    }
}

// ---- Pass 2: per-bucket row scan over G tiles (in place) + totals ----
__global__ void scan_rows_kernel(int* __restrict__ hist, int* __restrict__ tot, int G) {
    __shared__ int sh[SBLK];
    const int b = blockIdx.x, t = threadIdx.x;
    const int L = (G + SBLK - 1) / SBLK;
    const int lo = t * L;
    const int n = min(L, max(0, G - lo));
    const int base = b * G + lo;
    int s = 0;
    for (int k = 0; k < n; ++k) s += hist[base + k];
    sh[t] = s;
    __syncthreads();
    for (int off = 1; off < SBLK; off <<= 1) {
        int v = (t >= off) ? sh[t - off] : 0;
        __syncthreads();
        sh[t] += v;
        __syncthreads();
    }
    int excl = (t == 0) ? 0 : sh[t - 1];
    for (int k = 0; k < n; ++k) {
        int v = hist[base + k];
        hist[base + k] = excl;
        excl += v;
    }
    if (t == SBLK - 1) tot[b] = sh[SBLK - 1];
}

// ---- Pass 3: scan fine totals -> foff[0..NF]; fcnt = foff ----
__global__ void fscan_kernel(const int* __restrict__ tot4096,
                             int* __restrict__ foff, int* __restrict__ fcnt) {
    __shared__ int sh[SBLK];
    const int t = threadIdx.x;
    const int L = NF / SBLK;  // 16
    int loc[16];
    int s = 0;
    #pragma unroll
    for (int j = 0; j < L; ++j) { loc[j] = tot4096[t * L + j]; s += loc[j]; }
    sh[t] = s;
    __syncthreads();
    for (int o = 1; o < SBLK; o <<= 1) {
        int v = (t >= o) ? sh[t - o] : 0;
        __syncthreads();
        sh[t] += v;
        __syncthreads();
    }
    int run = (t == 0) ? 0 : sh[t - 1];
    #pragma unroll
    for (int j = 0; j < L; ++j) {
        foff[t * L + j] = run;
        fcnt[t * L + j] = run;
        run += loc[j];
    }
    if (t == SBLK - 1) foff[NF] = run;  // == N
}

// ---- Pass 4: direct-to-fine stable scatter. 2-phase, ~23 barriers/block.
// Wave w owns contiguous subrange [w*1024, (w+1)*1024) of the tile, so
// (wave, round, lane) order == index order -> stable coarse rank.
__global__ void __launch_bounds__(DBLK) scatterD_kernel(
        const float* __restrict__ xyz, const float* __restrict__ aabb,
        const float* __restrict__ dmin, const float* __restrict__ dmax,
        const int* __restrict__ hist64, const int* __restrict__ tot64,
        const int* __restrict__ hist2, int* __restrict__ fcnt,
        unsigned long long* __restrict__ payloadF, int N, int T) {
    __shared__ int   s_fb[NF];        // fine write cursors (16 KB)
    __shared__ int   s_wh[16][NB];    // per-wave bucket counts -> inclusive scan
    __shared__ int   s_cnt0[NB];      // global coarse base for this tile
    __shared__ int   s_off[NB];
    __shared__ float s_dn[192], s_sc[192];
    const int tid = threadIdx.x, g = blockIdx.x;
    const int lane = tid & 63, wv = tid >> 6;
    // fine-range reservations (global atomics issued early)
    for (int l = tid; l < NF; l += DBLK) {
        int c = hist2[(size_t)g * NF + l];
        s_fb[l] = c ? atomicAdd(&fcnt[l], c) : 0;
    }
    if (tid < NB) s_off[tid] = tot64[tid];
    if (tid < 192) { s_dn[tid] = dmin[tid]; s_sc[tid] = 63.0f / (dmax[tid] - dmin[tid]); }
    ((int*)s_wh)[tid] = 0;   // 16*64 == DBLK
    const float a0x = aabb[0], a0y = aabb[1], a0z = aabb[2];
    const float vx = (aabb[3] - a0x) * 0.25f;
    const float vy = (aabb[4] - a0y) * 0.25f;
    const float vz = (aabb[5] - a0z) * 0.25f;
    __syncthreads();
    // in-block scan of the 64 bucket totals -> global bucket offsets
    for (int o = 1; o < NB; o <<= 1) {
        int v = (tid < NB && tid >= o) ? s_off[tid - o] : 0;
        __syncthreads();
        if (tid < NB) s_off[tid] += v;
        __syncthreads();
    }
    if (tid < NB) s_cnt0[tid] = hist64[tid * T + g] + (tid ? s_off[tid - 1] : 0);

    const unsigned long long lt = (1ull << lane) - 1ull;
    const int base_i = g * TILE + wv * 1024;
    unsigned long long cache[16];
    // ---- phase 1: per-wave counting + local positions (no block barriers) ----
    #pragma unroll
    for (int r = 0; r < 16; ++r) {
        int i = base_i + r * 64 + lane;
        bool valid = (i < N);
        int b = 0, qx = 0, qy = 0, qz = 0, key;
        if (valid) {
            quant_point(xyz[3 * i], xyz[3 * i + 1], xyz[3 * i + 2],
                        a0x, a0y, a0z, vx, vy, vz, s_dn, s_sc, b, qx, qy, qz, key);
        }
        unsigned long long m = __ballot(valid);
        #pragma unroll
        for (int q = 0; q < 6; ++q) {
            unsigned long long bal = __ballot((b >> q) & 1);
            m &= ((b >> q) & 1) ? bal : ~bal;
        }
        int rank = __popcll(m & lt);
        int run = valid ? s_wh[wv][b] : 0;          // pre-round wave count of b
        if (valid && rank == 0) s_wh[wv][b] = run + __popcll(m);  // sole writer
        int localpos = run + rank;                  // index-ordered within wave
        cache[r] = (unsigned long long)(unsigned)qx
                 | ((unsigned long long)(unsigned)qy << 14)
                 | ((unsigned long long)(unsigned)qz << 28)
                 | ((unsigned long long)(unsigned)b  << 42)
                 | ((unsigned long long)(unsigned)localpos << 48);
    }
    __syncthreads();
    // ---- inclusive scan of s_wh over the wave dimension (16) ----
    for (int o = 1; o < 16; o <<= 1) {
        int v = (wv >= o) ? s_wh[wv - o][lane] : 0;
        __syncthreads();
        s_wh[wv][lane] += v;
        __syncthreads();
    }
    // ---- phase 2: streaming writes, no barriers ----
    #pragma unroll
    for (int r = 0; r < 16; ++r) {
        int i = base_i + r * 64 + lane;
        if (i < N) {
            unsigned long long cc = cache[r];
            int qx = (int)(cc & 16383), qy = (int)((cc >> 14) & 16383);
            int qz = (int)((cc >> 28) & 16383);
            int b = (int)((cc >> 42) & 63);
            int localpos = (int)((cc >> 48) & 1023);
            int pos = s_cnt0[b] + (wv ? s_wh[wv - 1][b] : 0) + localpos;
            int key = (b << 6) | ((qz >> 12) << 4) | ((qy >> 12) << 2) | (qx >> 12);
            int fpos = atomicAdd(&s_fb[key], 1);
            payloadF[fpos] = (unsigned long long)(unsigned)qx
                           | ((unsigned long long)(unsigned)qy << 14)
                           | ((unsigned long long)(unsigned)qz << 28)
                           | ((unsigned long long)(unsigned)pos << 42);
        }
    }
}

// ---- Pass 5: one block per fine cell; 17^3 halo in LDS; quantized taps ----
__global__ void __launch_bounds__(GBLK) gather_kernel(
        const float* __restrict__ vol,
        const unsigned long long* __restrict__ payloadF,
        const int* __restrict__ foff, float* __restrict__ out) {
    __shared__ float sv[17 * 17 * 17];
    const int tid = threadIdx.x;
    const int nb = gridDim.x, d = blockIdx.x;
    const int k = (nb % 8 == 0) ? (d % 8) * (nb / 8) + (d / 8) : d;  // XCD swizzle
    const int b = k >> 6;
    const int bz = ((k >> 4) & 3) * 16, by = ((k >> 2) & 3) * 16, bx = (k & 3) * 16;
    const float* vb = vol + ((size_t)b << 18);
    for (int l = tid; l < 17 * 17 * 17; l += GBLK) {
        int z = l / 289, r = l - z * 289, y = r / 17, x = r - y * 17;
        int gz = bz + z, gy = by + y, gx = bx + x;
        sv[l] = (gz < 64 && gy < 64 && gx < 64)
                    ? vb[(gz << 12) + (gy << 6) + gx] : 0.0f;
    }
    __syncthreads();
    const int lo = foff[k];
    const int n = foff[k + 1] - lo;
    for (int j = tid; j < n; j += GBLK) {
        unsigned long long p = payloadF[lo + j];
        int qx = (int)(p & 16383), qy = (int)((p >> 14) & 16383);
        int qz = (int)((p >> 28) & 16383);
        int pos = (int)(p >> 42);
        float wx = (qx & 255) * (1.0f / 256.0f);
        float wy = (qy & 255) * (1.0f / 256.0f);
        float wz = (qz & 255) * (1.0f / 256.0f);
        int lx = (qx >> 8) - bx, ly = (qy >> 8) - by, lz = (qz >> 8) - bz;
        int base = lz * 289 + ly * 17 + lx;
        float v000 = sv[base],       v001 = sv[base + 1];
        float v010 = sv[base + 17],  v011 = sv[base + 18];
        float v100 = sv[base + 289], v101 = sv[base + 290];
        float v110 = sv[base + 306], v111 = sv[base + 307];
        float c00 = v000 + wx * (v001 - v000);
        float c01 = v010 + wx * (v011 - v010);
        float c10 = v100 + wx * (v101 - v100);
        float c11 = v110 + wx * (v111 - v110);
        float c0 = c00 + wy * (c01 - c00);
        float c1 = c10 + wy * (c11 - c10);
        out[pos] = c0 + wz * (c1 - c0);
    }
}

// ---------------- fallback path (N > 2^22 or tiny ws): round-1 style ----------------
__global__ void fb_hist_kernel(const float* __restrict__ xyz,
                               const float* __restrict__ aabb,
                               int* __restrict__ hist, int N, int G) {
    __shared__ int s_h[NB];
    const int tid = threadIdx.x, g = blockIdx.x;
    if (tid < NB) s_h[tid] = 0;
    __syncthreads();
    const float a0x = aabb[0], a0y = aabb[1], a0z = aabb[2];
    const float vx = (aabb[3] - a0x) * 0.25f;
    const float vy = (aabb[4] - a0y) * 0.25f;
    const float vz = (aabb[5] - a0z) * 0.25f;
    for (int c = 0; c < FB_TILE / 256; ++c) {
        int i = g * FB_TILE + c * 256 + tid;
        if (i < N)
            atomicAdd(&s_h[compute_bid(xyz[3 * i], xyz[3 * i + 1], xyz[3 * i + 2],
                                       a0x, a0y, a0z, vx, vy, vz)], 1);
    }
    __syncthreads();
    if (tid < NB) hist[tid * G + g] = s_h[tid];
}

__global__ void fb_scatter_kernel(const float* __restrict__ xyz,
                                  const float* __restrict__ aabb,
                                  const float* __restrict__ dmin,
                                  const float* __restrict__ dmax,
                                  const float* __restrict__ vol,
                                  const int* __restrict__ hist,
                                  const int* __restrict__ tot64,
                                  float* __restrict__ out, int N, int G) {
    __shared__ int   s_cnt[NB], s_off[NB];
    __shared__ int   s_whist[4][NB];
    __shared__ float s_dn[192], s_sc[192];
    const int tid = threadIdx.x, g = blockIdx.x;
    if (tid < NB) s_off[tid] = tot64[tid];
    if (tid < 192) { s_dn[tid] = dmin[tid]; s_sc[tid] = 63.0f / (dmax[tid] - dmin[tid]); }
    __syncthreads();
    for (int o = 1; o < NB; o <<= 1) {
        int v = (tid < NB && tid >= o) ? s_off[tid - o] : 0;
        __syncthreads();
        if (tid < NB) s_off[tid] += v;
        __syncthreads();
    }
    if (tid < NB) s_cnt[tid] = hist[tid * G + g] + (tid ? s_off[tid - 1] : 0);
    const float a0x = aabb[0], a0y = aabb[1], a0z = aabb[2];
    const float vx = (aabb[3] - a0x) * 0.25f;
    const float vy = (aabb[4] - a0y) * 0.25f;
    const float vz = (aabb[5] - a0z) * 0.25f;
    __syncthreads();
    const int lane = tid & 63, wv = tid >> 6;
    const unsigned long long lt = (1ull << lane) - 1ull;
    for (int c = 0; c < FB_TILE / 256; ++c) {
        int i = g * FB_TILE + c * 256 + tid;
        bool valid = (i < N);
        int b = 0;
        float alpha = 0.0f;
        if (valid) {
            float px = xyz[3 * i], py = xyz[3 * i + 1], pz = xyz[3 * i + 2];
            b = compute_bid(px, py, pz, a0x, a0y, a0z, vx, vy, vz);
            float fx = (px - s_dn[3 * b])     * s_sc[3 * b];
            float fy = (py - s_dn[3 * b + 1]) * s_sc[3 * b + 1];
            float fz = (pz - s_dn[3 * b + 2]) * s_sc[3 * b + 2];
            float x0f = floorf(fx), y0f = floorf(fy), z0f = floorf(fz);
            float wx = fx - x0f, wy = fy - y0f, wz = fz - z0f;
            int x0 = (int)x0f, y0 = (int)y0f, z0 = (int)z0f;
            const float* vb = vol + ((size_t)b << 18);
            auto F = [&](int zi, int yi, int xi) -> float {
                if ((unsigned)zi >= 64u || (unsigned)yi >= 64u || (unsigned)xi >= 64u)
                    return 0.0f;
                return vb[(zi << 12) + (yi << 6) + xi];
            };
            float s = 0.0f;
            s += (1.0f - wz) * (1.0f - wy) * (1.0f - wx) * F(z0,     y0,     x0);
            s += (1.0f - wz) * (1.0f - wy) * wx          * F(z0,     y0,     x0 + 1);
            s += (1.0f - wz) * wy          * (1.0f - wx) * F(z0,     y0 + 1, x0);
            s += (1.0f - wz) * wy          * wx          * F(z0,     y0 + 1, x0 + 1);
            s += wz          * (1.0f - wy) * (1.0f - wx) * F(z0 + 1, y0,     x0);
            s += wz          * (1.0f - wy) * wx          * F(z0 + 1, y0,     x0 + 1);
            s += wz          * wy          * (1.0f - wx) * F(z0 + 1, y0 + 1, x0);
            s += wz          * wy          * wx          * F(z0 + 1, y0 + 1, x0 + 1);
            alpha = s;
        }
        ((int*)s_whist)[tid] = 0;
        __syncthreads();
        unsigned long long m = __ballot(valid);
        #pragma unroll
        for (int q = 0; q < 6; ++q) {
            unsigned long long bal = __ballot((b >> q) & 1);
            m &= ((b >> q) & 1) ? bal : ~bal;
        }
        int rank = __popcll(m & lt);
        if (valid && rank == 0) s_whist[wv][b] = __popcll(m);
        __syncthreads();
        if (valid) {
            int pos = s_cnt[b] + rank;
            for (int w2 = 0; w2 < wv; ++w2) pos += s_whist[w2][b];
            out[pos] = alpha;
        }
        __syncthreads();
        if (tid < NB)
            s_cnt[tid] += s_whist[0][tid] + s_whist[1][tid] +
                          s_whist[2][tid] + s_whist[3][tid];
        __syncthreads();
    }
}

extern "C" void kernel_launch(void* const* d_in, const int* in_sizes, int n_in,
                              void* d_out, int out_size, void* d_ws, size_t ws_size,
                              hipStream_t stream) {
    const float* xyz  = (const float*)d_in[0];
    const float* aabb = (const float*)d_in[1];
    const float* vol  = (const float*)d_in[2];
    const float* dmin = (const float*)d_in[3];
    const float* dmax = (const float*)d_in[4];
    float* out = (float*)d_out;
    const int N = in_sizes[0] / 3;
    const int T = (N + TILE - 1) / TILE;

    auto align = [](size_t x) { return (x + 255) & ~(size_t)255; };
    char* ws = (char*)d_ws;
    size_t o = 0;
    unsigned long long* payloadF = (unsigned long long*)(ws + o); o += align((size_t)N * 8);
    int* hist64  = (int*)(ws + o); o += align((size_t)NB * T * 4);
    int* tot64   = (int*)(ws + o); o += 256;
    int* hist2   = (int*)(ws + o); o += align((size_t)T * NF * 4);
    int* tot4096 = (int*)(ws + o); o += align((size_t)NF * 4);
    int* foff    = (int*)(ws + o); o += align((size_t)(NF + 1) * 4);
    int* fcnt    = (int*)(ws + o); o += align((size_t)NF * 4);
    const bool fine = (N <= (1 << 22)) && (ws_size >= o);

    if (fine) {
        hipMemsetAsync(tot4096, 0, NF * 4, stream);
        hist_kernel<<<T, HBLK, 0, stream>>>(xyz, aabb, dmin, dmax,
                                            hist64, hist2, tot4096, N, T);
        scan_rows_kernel<<<NB, SBLK, 0, stream>>>(hist64, tot64, T);
        fscan_kernel<<<1, SBLK, 0, stream>>>(tot4096, foff, fcnt);
        scatterD_kernel<<<T, DBLK, 0, stream>>>(xyz, aabb, dmin, dmax, hist64,
                                                tot64, hist2, fcnt, payloadF, N, T);
        gather_kernel<<<NF, GBLK, 0, stream>>>(vol, payloadF, foff, out);
    } else {
        const int Gf = (N + FB_TILE - 1) / FB_TILE;
        int* h = (int*)ws;
        int* t = (int*)(ws + align((size_t)NB * Gf * 4));
        fb_hist_kernel<<<Gf, 256, 0, stream>>>(xyz, aabb, h, N, Gf);
        scan_rows_kernel<<<NB, SBLK, 0, stream>>>(h, t, Gf);
        fb_scatter_kernel<<<Gf, 256, 0, stream>>>(xyz, aabb, dmin, dmax, vol,
                                                  h, t, out, N, Gf);
    }
}

// Round 8
// 279.259 us; speedup vs baseline: 1.9181x; 1.0029x over previous
//
#include <hip/hip_runtime.h>

#define NB     64
#define NF     4096
#define TILE   16384
#define HBLK   1024
#define DBLK   1024   // 16 waves
#define FBLK   512
#define GBLK   256
#define SBLK   256
#define FB_TILE 4096

// bit-exact bid (order-determining — plain divides, matches reference)
__device__ __forceinline__ int compute_bid(float px, float py, float pz,
                                           float a0x, float a0y, float a0z,
                                           float vx, float vy, float vz) {
    int ix = (int)floorf((px - a0x) / vx);
    int iy = (int)floorf((py - a0y) / vy);
    int iz = (int)floorf((pz - a0z) / vz);
    ix = min(max(ix, 0), 3);
    iy = min(max(iy, 0), 3);
    iz = min(max(iz, 0), 3);
    return ix * 16 + iy * 4 + iz;
}

// 14-bit fixed-point (8 frac bits) quantization; IDENTICAL in hist & scatterC.
__device__ __forceinline__ void quant_point(float px, float py, float pz,
        float a0x, float a0y, float a0z, float vx, float vy, float vz,
        const float* s_dn, const float* s_sc,
        int& b, int& qx, int& qy, int& qz, int& key) {
    b = compute_bid(px, py, pz, a0x, a0y, a0z, vx, vy, vz);
    float fx = (px - s_dn[3 * b])     * s_sc[3 * b];
    float fy = (py - s_dn[3 * b + 1]) * s_sc[3 * b + 1];
    float fz = (pz - s_dn[3 * b + 2]) * s_sc[3 * b + 2];
    qx = min(max(__float2int_rn(fx * 256.0f), 0), 16128);
    qy = min(max(__float2int_rn(fy * 256.0f), 0), 16128);
    qz = min(max(__float2int_rn(fz * 256.0f), 0), 16128);
    key = (b << 6) | ((qz >> 12) << 4) | ((qy >> 12) << 2) | (qx >> 12);
}

// ---- Pass 1: coarse per-tile hist (bucket-major) + global fine totals ----
__global__ void __launch_bounds__(HBLK) hist_kernel(
        const float* __restrict__ xyz, const float* __restrict__ aabb,
        const float* __restrict__ dmin, const float* __restrict__ dmax,
        int* __restrict__ hist64, int* __restrict__ tot4096, int N, int T) {
    __shared__ int   sh[NF];
    __shared__ float s_dn[192], s_sc[192];
    const int tid = threadIdx.x, g = blockIdx.x;
    for (int l = tid; l < NF; l += HBLK) sh[l] = 0;
    if (tid < 192) { s_dn[tid] = dmin[tid]; s_sc[tid] = 63.0f / (dmax[tid] - dmin[tid]); }
    const float a0x = aabb[0], a0y = aabb[1], a0z = aabb[2];
    const float vx = (aabb[3] - a0x) * 0.25f;
    const float vy = (aabb[4] - a0y) * 0.25f;
    const float vz = (aabb[5] - a0z) * 0.25f;
    __syncthreads();
    for (int c = 0; c < TILE / (HBLK * 4); ++c) {
        int p0 = g * TILE + c * (HBLK * 4) + tid * 4;
        int b, qx, qy, qz, k;
        if (p0 + 3 < N) {
            const float4* v4 = (const float4*)(xyz + (size_t)p0 * 3);
            float4 f0 = v4[0], f1 = v4[1], f2 = v4[2];
            quant_point(f0.x, f0.y, f0.z, a0x, a0y, a0z, vx, vy, vz, s_dn, s_sc, b, qx, qy, qz, k);
            atomicAdd(&sh[k], 1);
            quant_point(f0.w, f1.x, f1.y, a0x, a0y, a0z, vx, vy, vz, s_dn, s_sc, b, qx, qy, qz, k);
            atomicAdd(&sh[k], 1);
            quant_point(f1.z, f1.w, f2.x, a0x, a0y, a0z, vx, vy, vz, s_dn, s_sc, b, qx, qy, qz, k);
            atomicAdd(&sh[k], 1);
            quant_point(f2.y, f2.z, f2.w, a0x, a0y, a0z, vx, vy, vz, s_dn, s_sc, b, qx, qy, qz, k);
            atomicAdd(&sh[k], 1);
        } else {
            for (int t = 0; t < 4; ++t) {
                int i = p0 + t;
                if (i < N) {
                    quant_point(xyz[3 * i], xyz[3 * i + 1], xyz[3 * i + 2],
                                a0x, a0y, a0z, vx, vy, vz, s_dn, s_sc, b, qx, qy, qz, k);
                    atomicAdd(&sh[k], 1);
                }
            }
        }
    }
    __syncthreads();
    for (int l = tid; l < NF; l += HBLK) {
        int c = sh[l];
        if (c) atomicAdd(&tot4096[l], c);
    }
    if (tid < NB) {
        int s = 0;
        #pragma unroll
        for (int j = 0; j < 64; ++j) s += sh[tid * 64 + j];
        hist64[tid * T + g] = s;
    }
}

// ---- Pass 2: blocks 0..63 scan hist64 rows (in place, + tot64);
//      block 64 scans fine totals -> foff[0..NF], fcnt=foff ----
__global__ void scans_kernel(int* __restrict__ hist64, int* __restrict__ tot64,
                             const int* __restrict__ tot4096,
                             int* __restrict__ foff, int* __restrict__ fcnt, int G) {
    __shared__ int sh[SBLK];
    const int t = threadIdx.x;
    if (blockIdx.x < NB) {
        const int b = blockIdx.x;
        const int L = (G + SBLK - 1) / SBLK;
        const int lo = t * L;
        const int n = min(L, max(0, G - lo));
        const int base = b * G + lo;
        int s = 0;
        for (int k = 0; k < n; ++k) s += hist64[base + k];
        sh[t] = s;
        __syncthreads();
        for (int off = 1; off < SBLK; off <<= 1) {
            int v = (t >= off) ? sh[t - off] : 0;
            __syncthreads();
            sh[t] += v;
            __syncthreads();
        }
        int excl = (t == 0) ? 0 : sh[t - 1];
        for (int k = 0; k < n; ++k) {
            int v = hist64[base + k];
            hist64[base + k] = excl;
            excl += v;
        }
        if (t == SBLK - 1) tot64[b] = sh[SBLK - 1];
    } else {
        const int L = NF / SBLK;  // 16
        int loc[16];
        int s = 0;
        #pragma unroll
        for (int j = 0; j < L; ++j) { loc[j] = tot4096[t * L + j]; s += loc[j]; }
        sh[t] = s;
        __syncthreads();
        for (int o = 1; o < SBLK; o <<= 1) {
            int v = (t >= o) ? sh[t - o] : 0;
            __syncthreads();
            sh[t] += v;
            __syncthreads();
        }
        int run = (t == 0) ? 0 : sh[t - 1];
        #pragma unroll
        for (int j = 0; j < L; ++j) {
            foff[t * L + j] = run;
            fcnt[t * L + j] = run;
            run += loc[j];
        }
        if (t == SBLK - 1) foff[NF] = run;  // == N
    }
}

// ---- Pass 3: COARSE stable scatter, 2-phase barrier-light.
// payloadC[pos] = qx | qy<<14 | qz<<28 | b<<42 ; pos IS the output position.
// Per-tile bucket runs ~256 pts -> 2KB contiguous writes (amp ~1).
__global__ void __launch_bounds__(DBLK) scatterC_kernel(
        const float* __restrict__ xyz, const float* __restrict__ aabb,
        const float* __restrict__ dmin, const float* __restrict__ dmax,
        const int* __restrict__ hist64, const int* __restrict__ tot64,
        unsigned long long* __restrict__ payloadC, int N, int T) {
    __shared__ int   s_wh[16][NB];
    __shared__ int   s_cnt0[NB];
    __shared__ int   s_off[NB];
    __shared__ float s_dn[192], s_sc[192];
    const int tid = threadIdx.x, g = blockIdx.x;
    const int lane = tid & 63, wv = tid >> 6;
    if (tid < NB) s_off[tid] = tot64[tid];
    if (tid < 192) { s_dn[tid] = dmin[tid]; s_sc[tid] = 63.0f / (dmax[tid] - dmin[tid]); }
    ((int*)s_wh)[tid] = 0;   // 16*64 == DBLK
    const float a0x = aabb[0], a0y = aabb[1], a0z = aabb[2];
    const float vx = (aabb[3] - a0x) * 0.25f;
    const float vy = (aabb[4] - a0y) * 0.25f;
    const float vz = (aabb[5] - a0z) * 0.25f;
    __syncthreads();
    for (int o = 1; o < NB; o <<= 1) {
        int v = (tid < NB && tid >= o) ? s_off[tid - o] : 0;
        __syncthreads();
        if (tid < NB) s_off[tid] += v;
        __syncthreads();
    }
    if (tid < NB) s_cnt0[tid] = hist64[tid * T + g] + (tid ? s_off[tid - 1] : 0);

    const unsigned long long lt = (1ull << lane) - 1ull;
    const int base_i = g * TILE + wv * 1024;
    unsigned long long cache[16];
    // phase 1: per-wave counts + index-ordered local positions (no barriers)
    #pragma unroll
    for (int r = 0; r < 16; ++r) {
        int i = base_i + r * 64 + lane;
        bool valid = (i < N);
        int b = 0, qx = 0, qy = 0, qz = 0, key;
        if (valid) {
            quant_point(xyz[3 * i], xyz[3 * i + 1], xyz[3 * i + 2],
                        a0x, a0y, a0z, vx, vy, vz, s_dn, s_sc, b, qx, qy, qz, key);
        }
        unsigned long long m = __ballot(valid);
        #pragma unroll
        for (int q = 0; q < 6; ++q) {
            unsigned long long bal = __ballot((b >> q) & 1);
            m &= ((b >> q) & 1) ? bal : ~bal;
        }
        int rank = __popcll(m & lt);
        int run = valid ? s_wh[wv][b] : 0;
        if (valid && rank == 0) s_wh[wv][b] = run + __popcll(m);
        int localpos = run + rank;
        cache[r] = (unsigned long long)(unsigned)qx
                 | ((unsigned long long)(unsigned)qy << 14)
                 | ((unsigned long long)(unsigned)qz << 28)
                 | ((unsigned long long)(unsigned)b  << 42)
                 | ((unsigned long long)(unsigned)localpos << 48);
    }
    __syncthreads();
    // inclusive scan over the 16 waves
    for (int o = 1; o < 16; o <<= 1) {
        int v = (wv >= o) ? s_wh[wv - o][lane] : 0;
        __syncthreads();
        s_wh[wv][lane] += v;
        __syncthreads();
    }
    // phase 2: direct indexed writes, no barriers
    #pragma unroll
    for (int r = 0; r < 16; ++r) {
        int i = base_i + r * 64 + lane;
        if (i < N) {
            unsigned long long cc = cache[r];
            int b = (int)((cc >> 42) & 63);
            int localpos = (int)((cc >> 48) & 1023);
            int pos = s_cnt0[b] + (wv ? s_wh[wv - 1][b] : 0) + localpos;
            payloadC[pos] = cc & ((1ull << 48) - 1);  // qx,qy,qz,b
        }
    }
}

// ---- Pass 4: FINE scatter, fused hist+reserve+scatter on a contiguous
// coarse-sorted tile2. Runs ~256/cell -> 2KB writes (amp ~1). ----
__global__ void __launch_bounds__(FBLK) scatterF_kernel(
        const unsigned long long* __restrict__ payloadC,
        int* __restrict__ fcnt,
        unsigned long long* __restrict__ payloadF, int N) {
    __shared__ int s_fb[NF];  // 16 KB
    const int tid = threadIdx.x, t2 = blockIdx.x;
    for (int l = tid; l < NF; l += FBLK) s_fb[l] = 0;
    __syncthreads();
    const int lo = t2 * TILE;
    const int n = min(TILE, N - lo);
    for (int j = tid; j < n; j += FBLK) {
        unsigned long long p = payloadC[lo + j];
        int qx = (int)(p & 16383), qy = (int)((p >> 14) & 16383);
        int qz = (int)((p >> 28) & 16383), b = (int)((p >> 42) & 63);
        int key = (b << 6) | ((qz >> 12) << 4) | ((qy >> 12) << 2) | (qx >> 12);
        atomicAdd(&s_fb[key], 1);
    }
    __syncthreads();
    for (int l = tid; l < NF; l += FBLK) {
        int c = s_fb[l];
        s_fb[l] = c ? atomicAdd(&fcnt[l], c) : 0;   // reserve contiguous range
    }
    __syncthreads();
    for (int j = tid; j < n; j += FBLK) {           // L2-hot re-read
        unsigned long long p = payloadC[lo + j];
        int qx = (int)(p & 16383), qy = (int)((p >> 14) & 16383);
        int qz = (int)((p >> 28) & 16383), b = (int)((p >> 42) & 63);
        int key = (b << 6) | ((qz >> 12) << 4) | ((qy >> 12) << 2) | (qx >> 12);
        int fpos = atomicAdd(&s_fb[key], 1);
        payloadF[fpos] = (p & ((1ull << 42) - 1))
                       | ((unsigned long long)(unsigned)(lo + j) << 42);  // outpos
    }
}

// ---- Pass 5: one block per fine cell; 17^3 halo in LDS; quantized taps ----
__global__ void __launch_bounds__(GBLK) gather_kernel(
        const float* __restrict__ vol,
        const unsigned long long* __restrict__ payloadF,
        const int* __restrict__ foff, float* __restrict__ out) {
    __shared__ float sv[17 * 17 * 17];
    const int tid = threadIdx.x;
    const int nb = gridDim.x, d = blockIdx.x;
    const int k = (nb % 8 == 0) ? (d % 8) * (nb / 8) + (d / 8) : d;  // XCD swizzle
    const int b = k >> 6;
    const int bz = ((k >> 4) & 3) * 16, by = ((k >> 2) & 3) * 16, bx = (k & 3) * 16;
    const float* vb = vol + ((size_t)b << 18);
    for (int l = tid; l < 17 * 17 * 17; l += GBLK) {
        int z = l / 289, r = l - z * 289, y = r / 17, x = r - y * 17;
        int gz = bz + z, gy = by + y, gx = bx + x;
        sv[l] = (gz < 64 && gy < 64 && gx < 64)
                    ? vb[(gz << 12) + (gy << 6) + gx] : 0.0f;
    }
    __syncthreads();
    const int lo = foff[k];
    const int n = foff[k + 1] - lo;
    for (int j = tid; j < n; j += GBLK) {
        unsigned long long p = payloadF[lo + j];
        int qx = (int)(p & 16383), qy = (int)((p >> 14) & 16383);
        int qz = (int)((p >> 28) & 16383);
        int pos = (int)(p >> 42);
        float wx = (qx & 255) * (1.0f / 256.0f);
        float wy = (qy & 255) * (1.0f / 256.0f);
        float wz = (qz & 255) * (1.0f / 256.0f);
        int lx = (qx >> 8) - bx, ly = (qy >> 8) - by, lz = (qz >> 8) - bz;
        int base = lz * 289 + ly * 17 + lx;
        float v000 = sv[base],       v001 = sv[base + 1];
        float v010 = sv[base + 17],  v011 = sv[base + 18];
        float v100 = sv[base + 289], v101 = sv[base + 290];
        float v110 = sv[base + 306], v111 = sv[base + 307];
        float c00 = v000 + wx * (v001 - v000);
        float c01 = v010 + wx * (v011 - v010);
        float c10 = v100 + wx * (v101 - v100);
        float c11 = v110 + wx * (v111 - v110);
        float c0 = c00 + wy * (c01 - c00);
        float c1 = c10 + wy * (c11 - c10);
        out[pos] = c0 + wz * (c1 - c0);
    }
}

// ---------------- fallback path (N > 2^22 or tiny ws) ----------------
__global__ void fb_hist_kernel(const float* __restrict__ xyz,
                               const float* __restrict__ aabb,
                               int* __restrict__ hist, int N, int G) {
    __shared__ int s_h[NB];
    const int tid = threadIdx.x, g = blockIdx.x;
    if (tid < NB) s_h[tid] = 0;
    __syncthreads();
    const float a0x = aabb[0], a0y = aabb[1], a0z = aabb[2];
    const float vx = (aabb[3] - a0x) * 0.25f;
    const float vy = (aabb[4] - a0y) * 0.25f;
    const float vz = (aabb[5] - a0z) * 0.25f;
    for (int c = 0; c < FB_TILE / 256; ++c) {
        int i = g * FB_TILE + c * 256 + tid;
        if (i < N)
            atomicAdd(&s_h[compute_bid(xyz[3 * i], xyz[3 * i + 1], xyz[3 * i + 2],
                                       a0x, a0y, a0z, vx, vy, vz)], 1);
    }
    __syncthreads();
    if (tid < NB) hist[tid * G + g] = s_h[tid];
}

__global__ void fb_scan_kernel(int* __restrict__ hist, int* __restrict__ tot, int G) {
    __shared__ int sh[SBLK];
    const int b = blockIdx.x, t = threadIdx.x;
    const int L = (G + SBLK - 1) / SBLK;
    const int lo = t * L;
    const int n = min(L, max(0, G - lo));
    const int base = b * G + lo;
    int s = 0;
    for (int k = 0; k < n; ++k) s += hist[base + k];
    sh[t] = s;
    __syncthreads();
    for (int off = 1; off < SBLK; off <<= 1) {
        int v = (t >= off) ? sh[t - off] : 0;
        __syncthreads();
        sh[t] += v;
        __syncthreads();
    }
    int excl = (t == 0) ? 0 : sh[t - 1];
    for (int k = 0; k < n; ++k) {
        int v = hist[base + k];
        hist[base + k] = excl;
        excl += v;
    }
    if (t == SBLK - 1) tot[b] = sh[SBLK - 1];
}

__global__ void fb_scatter_kernel(const float* __restrict__ xyz,
                                  const float* __restrict__ aabb,
                                  const float* __restrict__ dmin,
                                  const float* __restrict__ dmax,
                                  const float* __restrict__ vol,
                                  const int* __restrict__ hist,
                                  const int* __restrict__ tot64,
                                  float* __restrict__ out, int N, int G) {
    __shared__ int   s_cnt[NB], s_off[NB];
    __shared__ int   s_whist[4][NB];
    __shared__ float s_dn[192], s_sc[192];
    const int tid = threadIdx.x, g = blockIdx.x;
    if (tid < NB) s_off[tid] = tot64[tid];
    if (tid < 192) { s_dn[tid] = dmin[tid]; s_sc[tid] = 63.0f / (dmax[tid] - dmin[tid]); }
    __syncthreads();
    for (int o = 1; o < NB; o <<= 1) {
        int v = (tid < NB && tid >= o) ? s_off[tid - o] : 0;
        __syncthreads();
        if (tid < NB) s_off[tid] += v;
        __syncthreads();
    }
    if (tid < NB) s_cnt[tid] = hist[tid * G + g] + (tid ? s_off[tid - 1] : 0);
    const float a0x = aabb[0], a0y = aabb[1], a0z = aabb[2];
    const float vx = (aabb[3] - a0x) * 0.25f;
    const float vy = (aabb[4] - a0y) * 0.25f;
    const float vz = (aabb[5] - a0z) * 0.25f;
    __syncthreads();
    const int lane = tid & 63, wv = tid >> 6;
    const unsigned long long lt = (1ull << lane) - 1ull;
    for (int c = 0; c < FB_TILE / 256; ++c) {
        int i = g * FB_TILE + c * 256 + tid;
        bool valid = (i < N);
        int b = 0;
        float alpha = 0.0f;
        if (valid) {
            float px = xyz[3 * i], py = xyz[3 * i + 1], pz = xyz[3 * i + 2];
            b = compute_bid(px, py, pz, a0x, a0y, a0z, vx, vy, vz);
            float fx = (px - s_dn[3 * b])     * s_sc[3 * b];
            float fy = (py - s_dn[3 * b + 1]) * s_sc[3 * b + 1];
            float fz = (pz - s_dn[3 * b + 2]) * s_sc[3 * b + 2];
            float x0f = floorf(fx), y0f = floorf(fy), z0f = floorf(fz);
            float wx = fx - x0f, wy = fy - y0f, wz = fz - z0f;
            int x0 = (int)x0f, y0 = (int)y0f, z0 = (int)z0f;
            const float* vb = vol + ((size_t)b << 18);
            auto F = [&](int zi, int yi, int xi) -> float {
                if ((unsigned)zi >= 64u || (unsigned)yi >= 64u || (unsigned)xi >= 64u)
                    return 0.0f;
                return vb[(zi << 12) + (yi << 6) + xi];
            };
            float s = 0.0f;
            s += (1.0f - wz) * (1.0f - wy) * (1.0f - wx) * F(z0,     y0,     x0);
            s += (1.0f - wz) * (1.0f - wy) * wx          * F(z0,     y0,     x0 + 1);
            s += (1.0f - wz) * wy          * (1.0f - wx) * F(z0,     y0 + 1, x0);
            s += (1.0f - wz) * wy          * wx          * F(z0,     y0 + 1, x0 + 1);
            s += wz          * (1.0f - wy) * (1.0f - wx) * F(z0 + 1, y0,     x0);
            s += wz          * (1.0f - wy) * wx          * F(z0 + 1, y0,     x0 + 1);
            s += wz          * wy          * (1.0f - wx) * F(z0 + 1, y0 + 1, x0);
            s += wz          * wy          * wx          * F(z0 + 1, y0 + 1, x0 + 1);
            alpha = s;
        }
        ((int*)s_whist)[tid] = 0;
        __syncthreads();
        unsigned long long m = __ballot(valid);
        #pragma unroll
        for (int q = 0; q < 6; ++q) {
            unsigned long long bal = __ballot((b >> q) & 1);
            m &= ((b >> q) & 1) ? bal : ~bal;
        }
        int rank = __popcll(m & lt);
        if (valid && rank == 0) s_whist[wv][b] = __popcll(m);
        __syncthreads();
        if (valid) {
            int pos = s_cnt[b] + rank;
            for (int w2 = 0; w2 < wv; ++w2) pos += s_whist[w2][b];
            out[pos] = alpha;
        }
        __syncthreads();
        if (tid < NB)
            s_cnt[tid] += s_whist[0][tid] + s_whist[1][tid] +
                          s_whist[2][tid] + s_whist[3][tid];
        __syncthreads();
    }
}

extern "C" void kernel_launch(void* const* d_in, const int* in_sizes, int n_in,
                              void* d_out, int out_size, void* d_ws, size_t ws_size,
                              hipStream_t stream) {
    const float* xyz  = (const float*)d_in[0];
    const float* aabb = (const float*)d_in[1];
    const float* vol  = (const float*)d_in[2];
    const float* dmin = (const float*)d_in[3];
    const float* dmax = (const float*)d_in[4];
    float* out = (float*)d_out;
    const int N = in_sizes[0] / 3;
    const int T = (N + TILE - 1) / TILE;

    auto align = [](size_t x) { return (x + 255) & ~(size_t)255; };
    char* ws = (char*)d_ws;
    size_t o = 0;
    unsigned long long* payloadC = (unsigned long long*)(ws + o); o += align((size_t)N * 8);
    unsigned long long* payloadF = (unsigned long long*)(ws + o); o += align((size_t)N * 8);
    int* hist64  = (int*)(ws + o); o += align((size_t)NB * T * 4);
    int* tot64   = (int*)(ws + o); o += 256;
    int* tot4096 = (int*)(ws + o); o += align((size_t)NF * 4);
    int* foff    = (int*)(ws + o); o += align((size_t)(NF + 1) * 4);
    int* fcnt    = (int*)(ws + o); o += align((size_t)NF * 4);
    const bool fine = (N <= (1 << 22)) && (ws_size >= o);

    if (fine) {
        hipMemsetAsync(tot4096, 0, NF * 4, stream);
        hist_kernel<<<T, HBLK, 0, stream>>>(xyz, aabb, dmin, dmax,
                                            hist64, tot4096, N, T);
        scans_kernel<<<NB + 1, SBLK, 0, stream>>>(hist64, tot64, tot4096,
                                                  foff, fcnt, T);
        scatterC_kernel<<<T, DBLK, 0, stream>>>(xyz, aabb, dmin, dmax,
                                                hist64, tot64, payloadC, N, T);
        scatterF_kernel<<<T, FBLK, 0, stream>>>(payloadC, fcnt, payloadF, N);
        gather_kernel<<<NF, GBLK, 0, stream>>>(vol, payloadF, foff, out);
    } else {
        const int Gf = (N + FB_TILE - 1) / FB_TILE;
        int* h = (int*)ws;
        int* t = (int*)(ws + align((size_t)NB * Gf * 4));
        fb_hist_kernel<<<Gf, 256, 0, stream>>>(xyz, aabb, h, N, Gf);
        fb_scan_kernel<<<NB, SBLK, 0, stream>>>(h, t, Gf);
        fb_scatter_kernel<<<Gf, 256, 0, stream>>>(xyz, aabb, dmin, dmax, vol,
                                                  h, t, out, N, Gf);
    }
}